// Round 1
// baseline (4534.890 us; speedup 1.0000x reference)
//
#include <hip/hip_runtime.h>

#define MTOK 32768   // 8*4096 tokens
#define CIN  512     // in_ch
#define EMB  256     // emb_ch
#define NCODE 1024
#define VQ   3

// ---------------- init ----------------
__global__ void init_k(double* loss_acc) {
    loss_acc[0] = 0.0;  // sum of min-dists over all stages/tokens
    loss_acc[1] = 0.0;  // sum (z - z_q)^2
}

// ---------------- ||v||^2 per code (fp64) ----------------
__global__ __launch_bounds__(64) void vnorm_k(const float* __restrict__ cb,
                                              double* __restrict__ vnorm) {
    int s = blockIdx.x;
    const float* row = cb + s * EMB;
    double acc = 0.0;
    for (int k = threadIdx.x; k < EMB; k += 64) { double v = (double)row[k]; acc += v * v; }
    #pragma unroll
    for (int off = 32; off > 0; off >>= 1) acc += __shfl_down(acc, off, 64);
    if (threadIdx.x == 0) vnorm[s] = acc;
}

// ---------------- zi = (z - z_q) @ W_in^T   (fp64 accumulate) ----------------
// A [MTOK, 512] generated on the fly, B = W [256, 512] row-major, C = zi [MTOK, 256]
__global__ __launch_bounds__(256) void zi_gemm_k(const float* __restrict__ z,
                                                 const float* __restrict__ zq,
                                                 const float* __restrict__ W,
                                                 float* __restrict__ zi, int stage0) {
    __shared__ float As[64][33];
    __shared__ float Bs[64][33];
    const int tid = threadIdx.x;
    const int ty = tid >> 4, tx = tid & 15;
    const int m0 = blockIdx.x * 64;
    const int n0 = blockIdx.y * 64;
    const int lrow = tid >> 5, lcol = tid & 31;
    double acc[4][4];
    #pragma unroll
    for (int i = 0; i < 4; ++i)
        #pragma unroll
        for (int j = 0; j < 4; ++j) acc[i][j] = 0.0;

    for (int k0 = 0; k0 < CIN; k0 += 32) {
        __syncthreads();
        #pragma unroll
        for (int t = 0; t < 8; ++t) {
            int r = lrow + 8 * t;
            int ga = (m0 + r) * CIN + k0 + lcol;
            float a = z[ga];
            if (!stage0) a -= zq[ga];
            As[r][lcol] = a;
            Bs[r][lcol] = W[(n0 + r) * CIN + k0 + lcol];
        }
        __syncthreads();
        #pragma unroll
        for (int k = 0; k < 32; ++k) {
            double a[4], b[4];
            #pragma unroll
            for (int i = 0; i < 4; ++i) a[i] = (double)As[ty * 4 + i][k];
            #pragma unroll
            for (int j = 0; j < 4; ++j) b[j] = (double)Bs[tx * 4 + j][k];
            #pragma unroll
            for (int i = 0; i < 4; ++i)
                #pragma unroll
                for (int j = 0; j < 4; ++j) acc[i][j] += a[i] * b[j];
        }
    }
    #pragma unroll
    for (int i = 0; i < 4; ++i) {
        float4 v = make_float4((float)acc[i][0], (float)acc[i][1],
                               (float)acc[i][2], (float)acc[i][3]);
        *reinterpret_cast<float4*>(&zi[(m0 + ty * 4 + i) * EMB + n0 + tx * 4]) = v;
    }
}

// ---------------- fused distance + argmin + loss (fp64 scores) ----------------
// 16 tokens per block; score_s = ||v_s||^2 - 2*zi.v_s (const ||zi||^2 dropped for argmin,
// added back for the loss value). First-index tiebreak == np.argmin.
__global__ __launch_bounds__(256) void dist_k(const float* __restrict__ zi,
                                              const float* __restrict__ cb,
                                              const double* __restrict__ vnorm,
                                              int* __restrict__ idx,
                                              int* __restrict__ idx_sum,
                                              double* __restrict__ loss_acc,
                                              int stage0, int cumprod) {
    __shared__ float zis[16][258];
    __shared__ float cbs[64][33];
    __shared__ double znorm_s[16];
    __shared__ double loss_s[16];
    const int tid = threadIdx.x;
    const int ty = tid >> 4, tx = tid & 15;
    const int m0 = blockIdx.x * 16;
    const int lrow = tid >> 5, lcol = tid & 31;

    // stage the 16 zi rows
    for (int r = 0; r < 16; ++r) zis[r][tid] = zi[(m0 + r) * EMB + tid];
    __syncthreads();

    // ||zi||^2 per token (fp64)
    {
        double s = 0.0;
        #pragma unroll
        for (int t = 0; t < 16; ++t) { double v = (double)zis[ty][tx + 16 * t]; s += v * v; }
        #pragma unroll
        for (int off = 1; off < 16; off <<= 1) s += __shfl_xor(s, off, 64);
        if (tx == 0) znorm_s[ty] = s;
    }

    double best = 1e300;
    int bestIdx = 0;
    for (int c0 = 0; c0 < NCODE; c0 += 64) {
        double dot[4] = {0.0, 0.0, 0.0, 0.0};
        for (int k0 = 0; k0 < EMB; k0 += 32) {
            __syncthreads();
            #pragma unroll
            for (int t = 0; t < 8; ++t)
                cbs[lrow + 8 * t][lcol] = cb[(c0 + lrow + 8 * t) * EMB + k0 + lcol];
            __syncthreads();
            #pragma unroll
            for (int k = 0; k < 32; ++k) {
                double a = (double)zis[ty][k0 + k];
                #pragma unroll
                for (int j = 0; j < 4; ++j) dot[j] += a * (double)cbs[tx + 16 * j][k];
            }
        }
        #pragma unroll
        for (int j = 0; j < 4; ++j) {
            int s = c0 + tx + 16 * j;            // ascending within thread
            double sc = vnorm[s] - 2.0 * dot[j];
            if (sc < best) { best = sc; bestIdx = s; }
        }
    }
    // reduce across the 16 lanes of each token group; lexicographic (score, idx)
    #pragma unroll
    for (int off = 1; off < 16; off <<= 1) {
        double ob = __shfl_xor(best, off, 64);
        int    oi = __shfl_xor(bestIdx, off, 64);
        if (ob < best || (ob == best && oi < bestIdx)) { best = ob; bestIdx = oi; }
    }
    if (tx == 0) {
        int m = m0 + ty;
        idx[m] = bestIdx;
        if (stage0) idx_sum[m] = bestIdx;
        else        idx_sum[m] += bestIdx * cumprod;
        loss_s[ty] = znorm_s[ty] + best;   // min squared distance
    }
    __syncthreads();
    if (tid == 0) {
        double s = 0.0;
        for (int r = 0; r < 16; ++r) s += loss_s[r];
        atomicAdd(loss_acc, s);
    }
}

// ---------------- z_q (+)= zq_gather @ W_out^T   (fp32 accumulate) ----------------
// A[m,k] = cb[idx[m], k], B = W_out [512, 256] row-major, C = z_q [MTOK, 512]
__global__ __launch_bounds__(256) void out_gemm_k(const float* __restrict__ cb,
                                                  const int* __restrict__ idx,
                                                  const float* __restrict__ W,
                                                  float* __restrict__ zq, int stage0) {
    __shared__ float As[64][33];
    __shared__ float Bs[64][33];
    __shared__ int idxs[64];
    const int tid = threadIdx.x;
    const int ty = tid >> 4, tx = tid & 15;
    const int m0 = blockIdx.x * 64;
    const int n0 = blockIdx.y * 64;
    const int lrow = tid >> 5, lcol = tid & 31;
    if (tid < 64) idxs[tid] = idx[m0 + tid];
    float acc[4][4];
    #pragma unroll
    for (int i = 0; i < 4; ++i)
        #pragma unroll
        for (int j = 0; j < 4; ++j) acc[i][j] = 0.0f;

    for (int k0 = 0; k0 < EMB; k0 += 32) {
        __syncthreads();
        #pragma unroll
        for (int t = 0; t < 8; ++t) {
            int r = lrow + 8 * t;
            As[r][lcol] = cb[idxs[r] * EMB + k0 + lcol];
            Bs[r][lcol] = W[(n0 + r) * EMB + k0 + lcol];
        }
        __syncthreads();
        #pragma unroll
        for (int k = 0; k < 32; ++k) {
            float a[4], b[4];
            #pragma unroll
            for (int i = 0; i < 4; ++i) a[i] = As[ty * 4 + i][k];
            #pragma unroll
            for (int j = 0; j < 4; ++j) b[j] = Bs[tx * 4 + j][k];
            #pragma unroll
            for (int i = 0; i < 4; ++i)
                #pragma unroll
                for (int j = 0; j < 4; ++j) acc[i][j] = fmaf(a[i], b[j], acc[i][j]);
        }
    }
    #pragma unroll
    for (int i = 0; i < 4; ++i) {
        int off = (m0 + ty * 4 + i) * CIN + n0 + tx * 4;
        float4 v;
        if (stage0) {
            v = make_float4(acc[i][0], acc[i][1], acc[i][2], acc[i][3]);
        } else {
            v = *reinterpret_cast<const float4*>(&zq[off]);
            v.x += acc[i][0]; v.y += acc[i][1]; v.z += acc[i][2]; v.w += acc[i][3];
        }
        *reinterpret_cast<float4*>(&zq[off]) = v;
    }
}

// ---------------- sum (z - z_q)^2 ----------------
__global__ __launch_bounds__(256) void sqred_k(const float* __restrict__ z,
                                               const float* __restrict__ zq,
                                               double* __restrict__ acc) {
    __shared__ double red[256];
    int i0 = blockIdx.x * 256 + threadIdx.x;
    int stride = gridDim.x * 256;
    double s = 0.0;
    for (int i = i0; i < MTOK * CIN; i += stride) {
        double d = (double)z[i] - (double)zq[i];
        s += d * d;
    }
    red[threadIdx.x] = s;
    __syncthreads();
    for (int off = 128; off > 0; off >>= 1) {
        if (threadIdx.x < off) red[threadIdx.x] += red[threadIdx.x + off];
        __syncthreads();
    }
    if (threadIdx.x == 0) atomicAdd(acc + 1, red[0]);
}

// ---------------- finalize: idx_sum -> float, loss ----------------
__global__ void final_k(const int* __restrict__ idx_sum,
                        const double* __restrict__ loss_acc,
                        float* __restrict__ out) {
    int i = blockIdx.x * blockDim.x + threadIdx.x;
    if (i < MTOK) out[MTOK * CIN + i] = (float)idx_sum[i];
    if (i == 0) {
        double loss = 2.0 * loss_acc[0] / (3.0 * (double)MTOK * (double)EMB)
                    + loss_acc[1] / ((double)MTOK * (double)CIN);
        out[MTOK * CIN + MTOK] = (float)loss;
    }
}

extern "C" void kernel_launch(void* const* d_in, const int* in_sizes, int n_in,
                              void* d_out, int out_size, void* d_ws, size_t ws_size,
                              hipStream_t stream) {
    const float* z     = (const float*)d_in[0];
    const float* W_in  = (const float*)d_in[1];
    const float* W_out = (const float*)d_in[2];
    const float* cbs   = (const float*)d_in[3];
    float* out = (float*)d_out;
    char* ws = (char*)d_ws;

    // ws layout
    double* vnorm    = (double*)ws;                              // 1024 * 8 = 8192 B
    double* loss_acc = (double*)(ws + 8192);                     // 2 * 8
    float*  zi       = (float*)(ws + 8256);                      // MTOK*EMB*4 = 33554432 B
    int*    idx      = (int*)(ws + 8256 + (size_t)MTOK * EMB * 4);
    int*    idx_sum  = (int*)(ws + 8256 + (size_t)MTOK * EMB * 4 + (size_t)MTOK * 4);

    float* zq = out;  // z_q lives directly in d_out[0 .. MTOK*CIN)

    init_k<<<dim3(1), dim3(1), 0, stream>>>(loss_acc);

    const int cumprod[VQ] = {1, 1024, 1024 * 1024};
    for (int i = 0; i < VQ; ++i) {
        const float* cb = cbs + (size_t)i * NCODE * EMB;
        vnorm_k<<<dim3(NCODE), dim3(64), 0, stream>>>(cb, vnorm);
        zi_gemm_k<<<dim3(MTOK / 64, EMB / 64), dim3(256), 0, stream>>>(
            z, zq, W_in + (size_t)i * EMB * CIN, zi, i == 0 ? 1 : 0);
        dist_k<<<dim3(MTOK / 16), dim3(256), 0, stream>>>(
            zi, cb, vnorm, idx, idx_sum, loss_acc, i == 0 ? 1 : 0, cumprod[i]);
        out_gemm_k<<<dim3(MTOK / 64, CIN / 64), dim3(256), 0, stream>>>(
            cb, idx, W_out + (size_t)i * CIN * EMB, zq, i == 0 ? 1 : 0);
    }
    sqred_k<<<dim3(2048), dim3(256), 0, stream>>>(z, zq, loss_acc);
    final_k<<<dim3(MTOK / 256), dim3(256), 0, stream>>>(idx_sum, loss_acc, out);
}

// Round 2
// 2470.863 us; speedup vs baseline: 1.8353x; 1.8353x over previous
//
#include <hip/hip_runtime.h>

#define MTOK 32768   // 8*4096 tokens
#define CIN  512     // in_ch
#define EMB  256     // emb_ch
#define NCODE 1024
#define VQ   3
#define DELTA 1e-3f  // >= 10x worst-case fp32 score error (256*eps*||zi||*||v|| ~ 1e-4)

// ---------------- init ----------------
__global__ void init_k(double* loss_acc, int* cnt) {
    loss_acc[0] = 0.0;  // sum of min-dists over all stages/tokens
    loss_acc[1] = 0.0;  // sum (z - z_q)^2
    cnt[0] = 0; cnt[1] = 0; cnt[2] = 0;
}

// ---------------- ||v||^2 per code (fp64 + fp32 copy) ----------------
__global__ __launch_bounds__(64) void vnorm_k(const float* __restrict__ cb,
                                              double* __restrict__ vnorm64,
                                              float* __restrict__ vnorm32) {
    int s = blockIdx.x;
    const float* row = cb + s * EMB;
    double acc = 0.0;
    for (int k = threadIdx.x; k < EMB; k += 64) { double v = (double)row[k]; acc += v * v; }
    #pragma unroll
    for (int off = 32; off > 0; off >>= 1) acc += __shfl_down(acc, off, 64);
    if (threadIdx.x == 0) { vnorm64[s] = acc; vnorm32[s] = (float)acc; }
}

// ---------------- zi = (z - z_q) @ W_in^T   (fp64 accumulate) ----------------
__global__ __launch_bounds__(256) void zi_gemm_k(const float* __restrict__ z,
                                                 const float* __restrict__ zq,
                                                 const float* __restrict__ W,
                                                 float* __restrict__ zi, int stage0) {
    __shared__ float As[64][33];
    __shared__ float Bs[64][33];
    const int tid = threadIdx.x;
    const int ty = tid >> 4, tx = tid & 15;
    const int m0 = blockIdx.x * 64;
    const int n0 = blockIdx.y * 64;
    const int lrow = tid >> 5, lcol = tid & 31;
    double acc[4][4];
    #pragma unroll
    for (int i = 0; i < 4; ++i)
        #pragma unroll
        for (int j = 0; j < 4; ++j) acc[i][j] = 0.0;

    for (int k0 = 0; k0 < CIN; k0 += 32) {
        __syncthreads();
        #pragma unroll
        for (int t = 0; t < 8; ++t) {
            int r = lrow + 8 * t;
            int ga = (m0 + r) * CIN + k0 + lcol;
            float a = z[ga];
            if (!stage0) a -= zq[ga];
            As[r][lcol] = a;
            Bs[r][lcol] = W[(n0 + r) * CIN + k0 + lcol];
        }
        __syncthreads();
        #pragma unroll
        for (int k = 0; k < 32; ++k) {
            double a[4], b[4];
            #pragma unroll
            for (int i = 0; i < 4; ++i) a[i] = (double)As[ty * 4 + i][k];
            #pragma unroll
            for (int j = 0; j < 4; ++j) b[j] = (double)Bs[tx * 4 + j][k];
            #pragma unroll
            for (int i = 0; i < 4; ++i)
                #pragma unroll
                for (int j = 0; j < 4; ++j) acc[i][j] += a[i] * b[j];
        }
    }
    #pragma unroll
    for (int i = 0; i < 4; ++i) {
        float4 v = make_float4((float)acc[i][0], (float)acc[i][1],
                               (float)acc[i][2], (float)acc[i][3]);
        *reinterpret_cast<float4*>(&zi[(m0 + ty * 4 + i) * EMB + n0 + tx * 4]) = v;
    }
}

// ---------------- fp32 prefilter: best + second-best per token ----------------
// Block: 32 tokens x all 1024 codes (looped 256 at a time). Thread (ty,tx):
// tokens {ty*2, ty*2+1}, codes {c0 + g*64 + tx*4 + j}. Flags tokens whose
// top-2 gap < DELTA for exact fp64 rescan.
__global__ __launch_bounds__(256) void pref_k(const float* __restrict__ zi,
                                              const float* __restrict__ cb,
                                              const float* __restrict__ vnorm32,
                                              int* __restrict__ idx,
                                              int* __restrict__ idx_sum,
                                              float* __restrict__ mind,
                                              int* __restrict__ flagged,
                                              int* __restrict__ cnt,
                                              double* __restrict__ loss_acc,
                                              int stage0, int cumprod) {
    __shared__ float zis[256][36];    // [k][token], pad 36 for banks + b64 align
    __shared__ float cbs[32][260];    // [k][code], pad 260 for banks + b128 align
    __shared__ float znorm_s[32];
    __shared__ float loss_s[32];
    const int tid = threadIdx.x;
    const int ty = tid >> 4, tx = tid & 15;
    const int m0 = blockIdx.x * 32;

    // stage zi transposed: zis[k][tok]
    {
        int tokb = tid >> 5;          // 0..7
        int kb = tid & 31;
        #pragma unroll
        for (int tt = 0; tt < 4; ++tt) {
            int t2 = tokb + 8 * tt;
            const float* src = zi + (size_t)(m0 + t2) * EMB;
            #pragma unroll
            for (int ss = 0; ss < 8; ++ss) {
                int k = kb + 32 * ss;
                zis[k][t2] = src[k];
            }
        }
    }
    __syncthreads();
    // ||zi||^2 per token (fp32)
    {
        int tok = tid >> 3, seg = tid & 7;
        float s = 0.f;
        #pragma unroll
        for (int kk = 0; kk < 32; ++kk) {
            float v = zis[seg * 32 + kk][tok];
            s += v * v;
        }
        s += __shfl_xor(s, 1, 64); s += __shfl_xor(s, 2, 64); s += __shfl_xor(s, 4, 64);
        if (seg == 0) znorm_s[tok] = s;
    }

    float b1[2] = {1e30f, 1e30f}, b2[2] = {1e30f, 1e30f};
    int   i1[2] = {0, 0};

    for (int c0 = 0; c0 < NCODE; c0 += 256) {
        float acc[2][16];
        #pragma unroll
        for (int i = 0; i < 2; ++i)
            #pragma unroll
            for (int q = 0; q < 16; ++q) acc[i][q] = 0.f;

        for (int k0 = 0; k0 < EMB; k0 += 32) {
            __syncthreads();
            // stage cbs[k][c] transposed, vectorized global reads along k
            {
                int kq = (tid & 7) * 4;
                int rbase = tid >> 3;
                #pragma unroll
                for (int t = 0; t < 8; ++t) {
                    int r = rbase + 32 * t;
                    float4 v = *reinterpret_cast<const float4*>(
                        &cb[(size_t)(c0 + r) * EMB + k0 + kq]);
                    cbs[kq + 0][r] = v.x; cbs[kq + 1][r] = v.y;
                    cbs[kq + 2][r] = v.z; cbs[kq + 3][r] = v.w;
                }
            }
            __syncthreads();
            #pragma unroll
            for (int k = 0; k < 32; ++k) {
                float2 a = *reinterpret_cast<const float2*>(&zis[k0 + k][ty * 2]);
                #pragma unroll
                for (int g = 0; g < 4; ++g) {
                    float4 b = *reinterpret_cast<const float4*>(&cbs[k][g * 64 + tx * 4]);
                    acc[0][g * 4 + 0] = fmaf(a.x, b.x, acc[0][g * 4 + 0]);
                    acc[0][g * 4 + 1] = fmaf(a.x, b.y, acc[0][g * 4 + 1]);
                    acc[0][g * 4 + 2] = fmaf(a.x, b.z, acc[0][g * 4 + 2]);
                    acc[0][g * 4 + 3] = fmaf(a.x, b.w, acc[0][g * 4 + 3]);
                    acc[1][g * 4 + 0] = fmaf(a.y, b.x, acc[1][g * 4 + 0]);
                    acc[1][g * 4 + 1] = fmaf(a.y, b.y, acc[1][g * 4 + 1]);
                    acc[1][g * 4 + 2] = fmaf(a.y, b.z, acc[1][g * 4 + 2]);
                    acc[1][g * 4 + 3] = fmaf(a.y, b.w, acc[1][g * 4 + 3]);
                }
            }
        }
        // scores + running best/second (ascending code order for tiebreak)
        #pragma unroll
        for (int i = 0; i < 2; ++i) {
            #pragma unroll
            for (int g = 0; g < 4; ++g) {
                #pragma unroll
                for (int j = 0; j < 4; ++j) {
                    int c = c0 + g * 64 + tx * 4 + j;
                    float sc = vnorm32[c] - 2.f * acc[i][g * 4 + j];
                    if (sc < b1[i]) { b2[i] = b1[i]; b1[i] = sc; i1[i] = c; }
                    else b2[i] = fminf(b2[i], sc);
                }
            }
        }
    }
    // cross-lane reduce over tx (16 lanes share a token pair)
    #pragma unroll
    for (int off = 1; off < 16; off <<= 1) {
        #pragma unroll
        for (int i = 0; i < 2; ++i) {
            float ob1 = __shfl_xor(b1[i], off, 64);
            int   oi1 = __shfl_xor(i1[i], off, 64);
            float ob2 = __shfl_xor(b2[i], off, 64);
            if (ob1 < b1[i] || (ob1 == b1[i] && oi1 < i1[i])) {
                b2[i] = fminf(b1[i], ob2); b1[i] = ob1; i1[i] = oi1;
            } else {
                b2[i] = fminf(b2[i], ob1);
            }
        }
    }
    __syncthreads();
    if (tx == 0) {
        #pragma unroll
        for (int i = 0; i < 2; ++i) {
            int m = m0 + ty * 2 + i;
            idx[m] = i1[i];
            if (stage0) idx_sum[m] = i1[i];
            else        idx_sum[m] += i1[i] * cumprod;
            float md = znorm_s[ty * 2 + i] + b1[i];
            mind[m] = md;
            loss_s[ty * 2 + i] = md;
            if (b2[i] - b1[i] < DELTA) {
                int slot = atomicAdd(cnt, 1);
                flagged[slot] = m;
            }
        }
    }
    __syncthreads();
    if (tid == 0) {
        double s = 0.0;
        for (int r = 0; r < 32; ++r) s += (double)loss_s[r];
        atomicAdd(loss_acc, s);
    }
}

// ---------------- exact fp64 rescan of flagged tokens ----------------
__global__ __launch_bounds__(256) void rescan_k(const float* __restrict__ zi,
                                                const float* __restrict__ cb,
                                                const double* __restrict__ vnorm64,
                                                const int* __restrict__ flagged,
                                                const int* __restrict__ cnt,
                                                int* __restrict__ idx,
                                                int* __restrict__ idx_sum,
                                                float* __restrict__ mind,
                                                double* __restrict__ loss_acc,
                                                int cumprod) {
    __shared__ float zr[256];
    __shared__ double sred[256];
    __shared__ int ired[256];
    int n = *cnt;
    for (int j = blockIdx.x; j < n; j += gridDim.x) {
        int m = flagged[j];
        __syncthreads();
        zr[threadIdx.x] = zi[(size_t)m * EMB + threadIdx.x];
        __syncthreads();
        double best = 1e300; int bi = 0;
        for (int jj = 0; jj < 4; ++jj) {
            int c = threadIdx.x * 4 + jj;   // ascending within thread
            const float* row = cb + (size_t)c * EMB;
            double d = 0.0;
            for (int k = 0; k < 256; ++k) d += (double)zr[k] * (double)row[k];
            double sc = vnorm64[c] - 2.0 * d;
            if (sc < best) { best = sc; bi = c; }
        }
        sred[threadIdx.x] = best; ired[threadIdx.x] = bi;
        __syncthreads();
        for (int off = 128; off > 0; off >>= 1) {
            if (threadIdx.x < off) {
                double ob = sred[threadIdx.x + off]; int oi = ired[threadIdx.x + off];
                if (ob < sred[threadIdx.x] ||
                    (ob == sred[threadIdx.x] && oi < ired[threadIdx.x])) {
                    sred[threadIdx.x] = ob; ired[threadIdx.x] = oi;
                }
            }
            __syncthreads();
        }
        if (threadIdx.x == 0) {
            int newI = ired[0], oldI = idx[m];
            if (newI != oldI) { idx[m] = newI; idx_sum[m] += (newI - oldI) * cumprod; }
            double zn = 0.0;
            for (int k = 0; k < 256; ++k) { double v = (double)zr[k]; zn += v * v; }
            double md = zn + sred[0];
            atomicAdd(loss_acc, md - (double)mind[m]);
            mind[m] = (float)md;
        }
        __syncthreads();
    }
}

// ---------------- z_q (+)= zq_gather @ W_out^T   (fp32 accumulate) ----------------
__global__ __launch_bounds__(256) void out_gemm_k(const float* __restrict__ cb,
                                                  const int* __restrict__ idx,
                                                  const float* __restrict__ W,
                                                  float* __restrict__ zq, int stage0) {
    __shared__ float As[64][33];
    __shared__ float Bs[64][33];
    __shared__ int idxs[64];
    const int tid = threadIdx.x;
    const int ty = tid >> 4, tx = tid & 15;
    const int m0 = blockIdx.x * 64;
    const int n0 = blockIdx.y * 64;
    const int lrow = tid >> 5, lcol = tid & 31;
    if (tid < 64) idxs[tid] = idx[m0 + tid];
    float acc[4][4];
    #pragma unroll
    for (int i = 0; i < 4; ++i)
        #pragma unroll
        for (int j = 0; j < 4; ++j) acc[i][j] = 0.0f;

    for (int k0 = 0; k0 < EMB; k0 += 32) {
        __syncthreads();
        #pragma unroll
        for (int t = 0; t < 8; ++t) {
            int r = lrow + 8 * t;
            As[r][lcol] = cb[idxs[r] * EMB + k0 + lcol];
            Bs[r][lcol] = W[(n0 + r) * EMB + k0 + lcol];
        }
        __syncthreads();
        #pragma unroll
        for (int k = 0; k < 32; ++k) {
            float a[4], b[4];
            #pragma unroll
            for (int i = 0; i < 4; ++i) a[i] = As[ty * 4 + i][k];
            #pragma unroll
            for (int j = 0; j < 4; ++j) b[j] = Bs[tx * 4 + j][k];
            #pragma unroll
            for (int i = 0; i < 4; ++i)
                #pragma unroll
                for (int j = 0; j < 4; ++j) acc[i][j] = fmaf(a[i], b[j], acc[i][j]);
        }
    }
    #pragma unroll
    for (int i = 0; i < 4; ++i) {
        int off = (m0 + ty * 4 + i) * CIN + n0 + tx * 4;
        float4 v;
        if (stage0) {
            v = make_float4(acc[i][0], acc[i][1], acc[i][2], acc[i][3]);
        } else {
            v = *reinterpret_cast<const float4*>(&zq[off]);
            v.x += acc[i][0]; v.y += acc[i][1]; v.z += acc[i][2]; v.w += acc[i][3];
        }
        *reinterpret_cast<float4*>(&zq[off]) = v;
    }
}

// ---------------- sum (z - z_q)^2 ----------------
__global__ __launch_bounds__(256) void sqred_k(const float* __restrict__ z,
                                               const float* __restrict__ zq,
                                               double* __restrict__ acc) {
    __shared__ double red[256];
    int i0 = blockIdx.x * 256 + threadIdx.x;
    int stride = gridDim.x * 256;
    double s = 0.0;
    for (int i = i0; i < MTOK * CIN; i += stride) {
        double d = (double)z[i] - (double)zq[i];
        s += d * d;
    }
    red[threadIdx.x] = s;
    __syncthreads();
    for (int off = 128; off > 0; off >>= 1) {
        if (threadIdx.x < off) red[threadIdx.x] += red[threadIdx.x + off];
        __syncthreads();
    }
    if (threadIdx.x == 0) atomicAdd(acc + 1, red[0]);
}

// ---------------- finalize: idx_sum -> float, loss ----------------
__global__ void final_k(const int* __restrict__ idx_sum,
                        const double* __restrict__ loss_acc,
                        float* __restrict__ out) {
    int i = blockIdx.x * blockDim.x + threadIdx.x;
    if (i < MTOK) out[MTOK * CIN + i] = (float)idx_sum[i];
    if (i == 0) {
        double loss = 2.0 * loss_acc[0] / (3.0 * (double)MTOK * (double)EMB)
                    + loss_acc[1] / ((double)MTOK * (double)CIN);
        out[MTOK * CIN + MTOK] = (float)loss;
    }
}

extern "C" void kernel_launch(void* const* d_in, const int* in_sizes, int n_in,
                              void* d_out, int out_size, void* d_ws, size_t ws_size,
                              hipStream_t stream) {
    const float* z     = (const float*)d_in[0];
    const float* W_in  = (const float*)d_in[1];
    const float* W_out = (const float*)d_in[2];
    const float* cbs   = (const float*)d_in[3];
    float* out = (float*)d_out;
    char* ws = (char*)d_ws;

    // ws layout
    double* vnorm64  = (double*)ws;                          // 8192 B
    double* loss_acc = (double*)(ws + 8192);                 // 16 B
    float*  vnorm32  = (float*)(ws + 8208);                  // 4096 B
    int*    cnt      = (int*)(ws + 12304);                   // 12 B (pad to 16)
    float*  zi       = (float*)(ws + 12320);                 // 33554432 B
    char*   p        = ws + 12320 + (size_t)MTOK * EMB * 4;
    int*    idx      = (int*)p;                              // 131072 B
    int*    idx_sum  = (int*)(p + 131072);                   // 131072 B
    int*    flagged  = (int*)(p + 262144);                   // 131072 B
    float*  mind     = (float*)(p + 393216);                 // 131072 B

    float* zq = out;  // z_q lives directly in d_out[0 .. MTOK*CIN)

    init_k<<<dim3(1), dim3(1), 0, stream>>>(loss_acc, cnt);

    const int cumprod[VQ] = {1, 1024, 1024 * 1024};
    for (int i = 0; i < VQ; ++i) {
        const float* cb = cbs + (size_t)i * NCODE * EMB;
        vnorm_k<<<dim3(NCODE), dim3(64), 0, stream>>>(cb, vnorm64, vnorm32);
        zi_gemm_k<<<dim3(MTOK / 64, EMB / 64), dim3(256), 0, stream>>>(
            z, zq, W_in + (size_t)i * EMB * CIN, zi, i == 0 ? 1 : 0);
        pref_k<<<dim3(MTOK / 32), dim3(256), 0, stream>>>(
            zi, cb, vnorm32, idx, idx_sum, mind, flagged, cnt + i, loss_acc,
            i == 0 ? 1 : 0, cumprod[i]);
        rescan_k<<<dim3(512), dim3(256), 0, stream>>>(
            zi, cb, vnorm64, flagged, cnt + i, idx, idx_sum, mind, loss_acc,
            cumprod[i]);
        out_gemm_k<<<dim3(MTOK / 64, CIN / 64), dim3(256), 0, stream>>>(
            cb, idx, W_out + (size_t)i * CIN * EMB, zq, i == 0 ? 1 : 0);
    }
    sqred_k<<<dim3(2048), dim3(256), 0, stream>>>(z, zq, loss_acc);
    final_k<<<dim3(MTOK / 256), dim3(256), 0, stream>>>(idx_sum, loss_acc, out);
}

// Round 3
// 2230.853 us; speedup vs baseline: 2.0328x; 1.1076x over previous
//
#include <hip/hip_runtime.h>

#define MTOK 32768   // 8*4096 tokens
#define CIN  512     // in_ch
#define EMB  256     // emb_ch
#define NCODE 1024
#define VQ   3
#define DELTA 1e-3f  // certified margin; bf16-split score error ~2e-6 << DELTA/2

typedef short s16x8 __attribute__((ext_vector_type(8)));
typedef float f32x4 __attribute__((ext_vector_type(4)));
typedef unsigned short u16;

static __device__ __forceinline__ u16 f2bf(float x) {
    unsigned int u = __float_as_uint(x);
    u += 0x7FFF + ((u >> 16) & 1);          // RNE
    return (u16)(u >> 16);
}
static __device__ __forceinline__ float bf2f(u16 h) {
    return __uint_as_float(((unsigned int)h) << 16);
}

// ---------------- init ----------------
__global__ void init_k(double* loss_acc, int* cnt) {
    loss_acc[0] = 0.0;  // sum of min-dists (znorm parts + score parts)
    loss_acc[1] = 0.0;  // sum (z - z_q)^2
    cnt[0] = 0; cnt[1] = 0; cnt[2] = 0;
}

// ---------------- codebook prep: ||v||^2 (fp64/fp32) + bf16 hi/lo split ----------------
__global__ __launch_bounds__(64) void prep_cb_k(const float* __restrict__ cbs,
                                                double* __restrict__ vnorm64,
                                                float* __restrict__ vnorm32,
                                                u16* __restrict__ cbh,
                                                u16* __restrict__ cbl) {
    int s = blockIdx.x;                       // 0 .. 3*NCODE-1
    const float* row = cbs + (size_t)s * EMB;
    double acc = 0.0;
    for (int k = threadIdx.x; k < EMB; k += 64) {
        float v = row[k];
        double vd = (double)v; acc += vd * vd;
        u16 h = f2bf(v);
        u16 l = f2bf(v - bf2f(h));
        cbh[(size_t)s * EMB + k] = h;
        cbl[(size_t)s * EMB + k] = l;
    }
    #pragma unroll
    for (int off = 32; off > 0; off >>= 1) acc += __shfl_down(acc, off, 64);
    if (threadIdx.x == 0) { vnorm64[s] = acc; vnorm32[s] = (float)acc; }
}

// ---------------- zi = (z - z_q) @ W_in^T  (fp64 acc) + sum||zi||^2 into loss ----------------
__global__ __launch_bounds__(256) void zi_gemm_k(const float* __restrict__ z,
                                                 const float* __restrict__ zq,
                                                 const float* __restrict__ W,
                                                 float* __restrict__ zi,
                                                 double* __restrict__ loss_acc,
                                                 int stage0) {
    __shared__ float As[64][33];
    __shared__ float Bs[64][33];
    __shared__ double red[256];
    const int tid = threadIdx.x;
    const int ty = tid >> 4, tx = tid & 15;
    const int m0 = blockIdx.x * 64;
    const int n0 = blockIdx.y * 64;
    const int lrow = tid >> 5, lcol = tid & 31;
    double acc[4][4];
    #pragma unroll
    for (int i = 0; i < 4; ++i)
        #pragma unroll
        for (int j = 0; j < 4; ++j) acc[i][j] = 0.0;

    for (int k0 = 0; k0 < CIN; k0 += 32) {
        __syncthreads();
        #pragma unroll
        for (int t = 0; t < 8; ++t) {
            int r = lrow + 8 * t;
            int ga = (m0 + r) * CIN + k0 + lcol;
            float a = z[ga];
            if (!stage0) a -= zq[ga];
            As[r][lcol] = a;
            Bs[r][lcol] = W[(n0 + r) * CIN + k0 + lcol];
        }
        __syncthreads();
        #pragma unroll
        for (int k = 0; k < 32; ++k) {
            double a[4], b[4];
            #pragma unroll
            for (int i = 0; i < 4; ++i) a[i] = (double)As[ty * 4 + i][k];
            #pragma unroll
            for (int j = 0; j < 4; ++j) b[j] = (double)Bs[tx * 4 + j][k];
            #pragma unroll
            for (int i = 0; i < 4; ++i)
                #pragma unroll
                for (int j = 0; j < 4; ++j) acc[i][j] += a[i] * b[j];
        }
    }
    double zn = 0.0;
    #pragma unroll
    for (int i = 0; i < 4; ++i) {
        float4 v = make_float4((float)acc[i][0], (float)acc[i][1],
                               (float)acc[i][2], (float)acc[i][3]);
        *reinterpret_cast<float4*>(&zi[(m0 + ty * 4 + i) * EMB + n0 + tx * 4]) = v;
        #pragma unroll
        for (int j = 0; j < 4; ++j) zn += acc[i][j] * acc[i][j];
    }
    red[tid] = zn;
    __syncthreads();
    for (int off = 128; off > 0; off >>= 1) {
        if (tid < off) red[tid] += red[tid + off];
        __syncthreads();
    }
    if (tid == 0) atomicAdd(loss_acc, red[0]);
}

// ---------------- MFMA bf16-split prefilter: best + second-best per token ----------------
// Grid MTOK/64 blocks x 4 waves; wave w owns tokens mw..mw+15, scans all 1024 codes.
// score = ||v||^2 - 2*(zih.cbh + zil.cbh + zih.cbl); near-ties (gap<DELTA) -> fp64 rescan.
__global__ __launch_bounds__(256) void pref_k(const float* __restrict__ zi,
                                              const u16* __restrict__ cbh,
                                              const u16* __restrict__ cbl,
                                              const float* __restrict__ vnorm32,
                                              int* __restrict__ idx,
                                              int* __restrict__ idx_sum,
                                              float* __restrict__ mind,
                                              int* __restrict__ flagged,
                                              int* __restrict__ cnt,
                                              double* __restrict__ loss_acc,
                                              int stage0, int cumprod) {
    __shared__ double loss_s[16];
    const int tid = threadIdx.x;
    const int w = tid >> 6;
    const int l = tid & 63;
    const int col = l & 15;      // A-row sel / B-col / C-col
    const int g = l >> 4;        // k-slot group; C row-group
    const int mw = blockIdx.x * 64 + w * 16;

    // Build A fragments: bf16 hi/lo split of zi row (mw+col), k = 32*kc + 8*g + j
    s16x8 ah[8], al[8];
    {
        const float* zr = zi + (size_t)(mw + col) * EMB + g * 8;
        #pragma unroll
        for (int kc = 0; kc < 8; ++kc) {
            float4 f0 = *reinterpret_cast<const float4*>(zr + kc * 32);
            float4 f1 = *reinterpret_cast<const float4*>(zr + kc * 32 + 4);
            float f[8] = {f0.x, f0.y, f0.z, f0.w, f1.x, f1.y, f1.z, f1.w};
            #pragma unroll
            for (int j = 0; j < 8; ++j) {
                u16 h = f2bf(f[j]);
                u16 lo = f2bf(f[j] - bf2f(h));
                ah[kc][j] = (short)h;
                al[kc][j] = (short)lo;
            }
        }
    }

    float b1[4] = {1e30f, 1e30f, 1e30f, 1e30f};
    float b2[4] = {1e30f, 1e30f, 1e30f, 1e30f};
    int   i1[4] = {0, 0, 0, 0};

    for (int ct = 0; ct < 64; ++ct) {
        const u16* bh = cbh + (size_t)(ct * 16 + col) * EMB + g * 8;
        const u16* bl = cbl + (size_t)(ct * 16 + col) * EMB + g * 8;
        s16x8 Bh[8], Bl[8];
        #pragma unroll
        for (int kc = 0; kc < 8; ++kc) {
            Bh[kc] = *reinterpret_cast<const s16x8*>(bh + kc * 32);
            Bl[kc] = *reinterpret_cast<const s16x8*>(bl + kc * 32);
        }
        f32x4 acc = {0.f, 0.f, 0.f, 0.f};
        #pragma unroll
        for (int kc = 0; kc < 8; ++kc)
            acc = __builtin_amdgcn_mfma_f32_16x16x32_bf16(ah[kc], Bh[kc], acc, 0, 0, 0);
        #pragma unroll
        for (int kc = 0; kc < 8; ++kc)
            acc = __builtin_amdgcn_mfma_f32_16x16x32_bf16(al[kc], Bh[kc], acc, 0, 0, 0);
        #pragma unroll
        for (int kc = 0; kc < 8; ++kc)
            acc = __builtin_amdgcn_mfma_f32_16x16x32_bf16(ah[kc], Bl[kc], acc, 0, 0, 0);
        const float vn = vnorm32[ct * 16 + col];
        #pragma unroll
        for (int r = 0; r < 4; ++r) {
            float sc = vn - 2.f * acc[r];
            if (sc < b1[r]) { b2[r] = b1[r]; b1[r] = sc; i1[r] = ct * 16 + col; }
            else b2[r] = fminf(b2[r], sc);
        }
    }
    // reduce across the 16 lanes of each group (same 4 tokens, different cols)
    #pragma unroll
    for (int off = 1; off < 16; off <<= 1) {
        #pragma unroll
        for (int r = 0; r < 4; ++r) {
            float ob1 = __shfl_xor(b1[r], off, 64);
            int   oi1 = __shfl_xor(i1[r], off, 64);
            float ob2 = __shfl_xor(b2[r], off, 64);
            if (ob1 < b1[r] || (ob1 == b1[r] && oi1 < i1[r])) {
                b2[r] = fminf(b1[r], ob2); b1[r] = ob1; i1[r] = oi1;
            } else {
                b2[r] = fminf(b2[r], ob1);
            }
        }
    }
    if (col == 0) {
        double lsum = 0.0;
        #pragma unroll
        for (int r = 0; r < 4; ++r) {
            int m = mw + g * 4 + r;
            idx[m] = i1[r];
            if (stage0) idx_sum[m] = i1[r];
            else        idx_sum[m] += i1[r] * cumprod;
            mind[m] = b1[r];                 // score-only (znorm added separately)
            lsum += (double)b1[r];
            if (b2[r] - b1[r] < DELTA) {
                int slot = atomicAdd(cnt, 1);
                flagged[slot] = m;
            }
        }
        loss_s[w * 4 + g] = lsum;
    }
    __syncthreads();
    if (tid == 0) {
        double s = 0.0;
        #pragma unroll
        for (int q = 0; q < 16; ++q) s += loss_s[q];
        atomicAdd(loss_acc, s);
    }
}

// ---------------- exact fp64 rescan of flagged tokens ----------------
__global__ __launch_bounds__(256) void rescan_k(const float* __restrict__ zi,
                                                const float* __restrict__ cb,
                                                const double* __restrict__ vnorm64,
                                                const int* __restrict__ flagged,
                                                const int* __restrict__ cnt,
                                                int* __restrict__ idx,
                                                int* __restrict__ idx_sum,
                                                float* __restrict__ mind,
                                                double* __restrict__ loss_acc,
                                                int cumprod) {
    __shared__ float zr[256];
    __shared__ double sred[256];
    __shared__ int ired[256];
    int n = *cnt;
    for (int j = blockIdx.x; j < n; j += gridDim.x) {
        int m = flagged[j];
        __syncthreads();
        zr[threadIdx.x] = zi[(size_t)m * EMB + threadIdx.x];
        __syncthreads();
        double best = 1e300; int bi = 0;
        for (int jj = 0; jj < 4; ++jj) {
            int c = threadIdx.x * 4 + jj;   // ascending within thread
            const float* row = cb + (size_t)c * EMB;
            double d = 0.0;
            for (int k = 0; k < 256; ++k) d += (double)zr[k] * (double)row[k];
            double sc = vnorm64[c] - 2.0 * d;
            if (sc < best) { best = sc; bi = c; }
        }
        sred[threadIdx.x] = best; ired[threadIdx.x] = bi;
        __syncthreads();
        for (int off = 128; off > 0; off >>= 1) {
            if (threadIdx.x < off) {
                double ob = sred[threadIdx.x + off]; int oi = ired[threadIdx.x + off];
                if (ob < sred[threadIdx.x] ||
                    (ob == sred[threadIdx.x] && oi < ired[threadIdx.x])) {
                    sred[threadIdx.x] = ob; ired[threadIdx.x] = oi;
                }
            }
            __syncthreads();
        }
        if (threadIdx.x == 0) {
            int newI = ired[0], oldI = idx[m];
            if (newI != oldI) { idx[m] = newI; idx_sum[m] += (newI - oldI) * cumprod; }
            atomicAdd(loss_acc, sred[0] - (double)mind[m]);
            mind[m] = (float)sred[0];
        }
        __syncthreads();
    }
}

// ---------------- z_q (+)= gather(cb) @ W_out^T   (fp32 acc) ----------------
__global__ __launch_bounds__(256) void out_gemm_k(const float* __restrict__ cb,
                                                  const int* __restrict__ idx,
                                                  const float* __restrict__ W,
                                                  float* __restrict__ zq, int stage0) {
    __shared__ float As[64][33];
    __shared__ float Bs[64][33];
    __shared__ int idxs[64];
    const int tid = threadIdx.x;
    const int ty = tid >> 4, tx = tid & 15;
    const int m0 = blockIdx.x * 64;
    const int n0 = blockIdx.y * 64;
    const int lrow = tid >> 5, lcol = tid & 31;
    if (tid < 64) idxs[tid] = idx[m0 + tid];
    float acc[4][4];
    #pragma unroll
    for (int i = 0; i < 4; ++i)
        #pragma unroll
        for (int j = 0; j < 4; ++j) acc[i][j] = 0.0f;

    for (int k0 = 0; k0 < EMB; k0 += 32) {
        __syncthreads();
        #pragma unroll
        for (int t = 0; t < 8; ++t) {
            int r = lrow + 8 * t;
            As[r][lcol] = cb[idxs[r] * EMB + k0 + lcol];
            Bs[r][lcol] = W[(n0 + r) * EMB + k0 + lcol];
        }
        __syncthreads();
        #pragma unroll
        for (int k = 0; k < 32; ++k) {
            float a[4], b[4];
            #pragma unroll
            for (int i = 0; i < 4; ++i) a[i] = As[ty * 4 + i][k];
            #pragma unroll
            for (int j = 0; j < 4; ++j) b[j] = Bs[tx * 4 + j][k];
            #pragma unroll
            for (int i = 0; i < 4; ++i)
                #pragma unroll
                for (int j = 0; j < 4; ++j) acc[i][j] = fmaf(a[i], b[j], acc[i][j]);
        }
    }
    #pragma unroll
    for (int i = 0; i < 4; ++i) {
        int off = (m0 + ty * 4 + i) * CIN + n0 + tx * 4;
        float4 v;
        if (stage0) {
            v = make_float4(acc[i][0], acc[i][1], acc[i][2], acc[i][3]);
        } else {
            v = *reinterpret_cast<const float4*>(&zq[off]);
            v.x += acc[i][0]; v.y += acc[i][1]; v.z += acc[i][2]; v.w += acc[i][3];
        }
        *reinterpret_cast<float4*>(&zq[off]) = v;
    }
}

// ---------------- sum (z - z_q)^2 ----------------
__global__ __launch_bounds__(256) void sqred_k(const float* __restrict__ z,
                                               const float* __restrict__ zq,
                                               double* __restrict__ acc) {
    __shared__ double red[256];
    int i0 = blockIdx.x * 256 + threadIdx.x;
    int stride = gridDim.x * 256;
    double s = 0.0;
    for (int i = i0; i < MTOK * CIN; i += stride) {
        double d = (double)z[i] - (double)zq[i];
        s += d * d;
    }
    red[threadIdx.x] = s;
    __syncthreads();
    for (int off = 128; off > 0; off >>= 1) {
        if (threadIdx.x < off) red[threadIdx.x] += red[threadIdx.x + off];
        __syncthreads();
    }
    if (threadIdx.x == 0) atomicAdd(acc + 1, red[0]);
}

// ---------------- finalize ----------------
__global__ void final_k(const int* __restrict__ idx_sum,
                        const double* __restrict__ loss_acc,
                        float* __restrict__ out) {
    int i = blockIdx.x * blockDim.x + threadIdx.x;
    if (i < MTOK) out[MTOK * CIN + i] = (float)idx_sum[i];
    if (i == 0) {
        double loss = 2.0 * loss_acc[0] / (3.0 * (double)MTOK * (double)EMB)
                    + loss_acc[1] / ((double)MTOK * (double)CIN);
        out[MTOK * CIN + MTOK] = (float)loss;
    }
}

extern "C" void kernel_launch(void* const* d_in, const int* in_sizes, int n_in,
                              void* d_out, int out_size, void* d_ws, size_t ws_size,
                              hipStream_t stream) {
    const float* z     = (const float*)d_in[0];
    const float* W_in  = (const float*)d_in[1];
    const float* W_out = (const float*)d_in[2];
    const float* cbs   = (const float*)d_in[3];
    float* out = (float*)d_out;
    char* ws = (char*)d_ws;

    // ws layout (16B-aligned offsets)
    double* vnorm64  = (double*)ws;                               // 3*1024*8 = 24576
    double* loss_acc = (double*)(ws + 24576);                     // 16
    float*  vnorm32  = (float*)(ws + 24592);                      // 3*1024*4 = 12288
    int*    cnt      = (int*)(ws + 36880);                        // 16
    u16*    cbh      = (u16*)(ws + 36896);                        // 3*1024*256*2 = 1572864
    u16*    cbl      = (u16*)(ws + 1609760);                      // 1572864
    float*  zi       = (float*)(ws + 3182624);                    // 33554432
    char*   p        = ws + 3182624 + (size_t)MTOK * EMB * 4;
    int*    idx      = (int*)p;                                   // 131072
    int*    idx_sum  = (int*)(p + 131072);                        // 131072
    int*    flagged  = (int*)(p + 262144);                        // 131072
    float*  mind     = (float*)(p + 393216);                      // 131072

    float* zq = out;  // z_q lives in d_out[0 .. MTOK*CIN)

    init_k<<<dim3(1), dim3(1), 0, stream>>>(loss_acc, cnt);
    prep_cb_k<<<dim3(VQ * NCODE), dim3(64), 0, stream>>>(cbs, vnorm64, vnorm32, cbh, cbl);

    const int cumprod[VQ] = {1, 1024, 1024 * 1024};
    for (int i = 0; i < VQ; ++i) {
        const float* cb = cbs + (size_t)i * NCODE * EMB;
        zi_gemm_k<<<dim3(MTOK / 64, EMB / 64), dim3(256), 0, stream>>>(
            z, zq, W_in + (size_t)i * EMB * CIN, zi, loss_acc, i == 0 ? 1 : 0);
        pref_k<<<dim3(MTOK / 64), dim3(256), 0, stream>>>(
            zi, cbh + (size_t)i * NCODE * EMB, cbl + (size_t)i * NCODE * EMB,
            vnorm32 + i * NCODE, idx, idx_sum, mind, flagged, cnt + i, loss_acc,
            i == 0 ? 1 : 0, cumprod[i]);
        rescan_k<<<dim3(512), dim3(256), 0, stream>>>(
            zi, cb, vnorm64 + i * NCODE, flagged, cnt + i, idx, idx_sum, mind,
            loss_acc, cumprod[i]);
        out_gemm_k<<<dim3(MTOK / 64, CIN / 64), dim3(256), 0, stream>>>(
            cb, idx, W_out + (size_t)i * CIN * EMB, zq, i == 0 ? 1 : 0);
    }
    sqred_k<<<dim3(2048), dim3(256), 0, stream>>>(z, zq, loss_acc);
    final_k<<<dim3(MTOK / 256), dim3(256), 0, stream>>>(idx_sum, loss_acc, out);
}

// Round 4
// 1833.103 us; speedup vs baseline: 2.4739x; 1.2170x over previous
//
#include <hip/hip_runtime.h>

#define MTOK 32768   // 8*4096 tokens
#define CIN  512     // in_ch
#define EMB  256     // emb_ch
#define NCODE 1024
#define VQ   3
#define DELTA 2e-3f  // certified margin; worst-case approx score-diff error ~2e-4

typedef short s16x8 __attribute__((ext_vector_type(8)));
typedef float f32x4 __attribute__((ext_vector_type(4)));
typedef unsigned short u16;

static __device__ __forceinline__ u16 f2bf(float x) {
    unsigned int u = __float_as_uint(x);
    u += 0x7FFF + ((u >> 16) & 1);          // RNE
    return (u16)(u >> 16);
}
static __device__ __forceinline__ float bf2f(u16 h) {
    return __uint_as_float(((unsigned int)h) << 16);
}

// ---------------- init ----------------
__global__ void init_k(double* loss_acc, int* cnt) {
    loss_acc[0] = 0.0;  // sum of min-dists (znorm parts + score parts)
    loss_acc[1] = 0.0;  // sum (z - z_q)^2
    cnt[0] = 0; cnt[1] = 0; cnt[2] = 0;
}

// ---------------- codebook prep: ||v||^2 (fp64/fp32) + bf16 hi/lo split ----------------
__global__ __launch_bounds__(64) void prep_cb_k(const float* __restrict__ cbs,
                                                double* __restrict__ vnorm64,
                                                float* __restrict__ vnorm32,
                                                u16* __restrict__ cbh,
                                                u16* __restrict__ cbl) {
    int s = blockIdx.x;                       // 0 .. 3*NCODE-1
    const float* row = cbs + (size_t)s * EMB;
    double acc = 0.0;
    for (int k = threadIdx.x; k < EMB; k += 64) {
        float v = row[k];
        double vd = (double)v; acc += vd * vd;
        u16 h = f2bf(v);
        u16 l = f2bf(v - bf2f(h));
        cbh[(size_t)s * EMB + k] = h;
        cbl[(size_t)s * EMB + k] = l;
    }
    #pragma unroll
    for (int off = 32; off > 0; off >>= 1) acc += __shfl_down(acc, off, 64);
    if (threadIdx.x == 0) { vnorm64[s] = acc; vnorm32[s] = (float)acc; }
}

// ---------------- W_in bf16 hi/lo split ----------------
__global__ __launch_bounds__(256) void prep_w_k(const float* __restrict__ W_in,
                                                u16* __restrict__ wh,
                                                u16* __restrict__ wl) {
    int i = blockIdx.x * 256 + threadIdx.x;   // < VQ*EMB*CIN
    float v = W_in[i];
    u16 h = f2bf(v);
    wh[i] = h;
    wl[i] = f2bf(v - bf2f(h));
}

// ---------------- T[s] = cb[s] @ W_out[s]^T  (fp64 acc, fp32 store) ----------------
// A = cb [1024][256], B = W_out [512][256], C = T [1024][512]
__global__ __launch_bounds__(256) void prep_T_k(const float* __restrict__ cbs,
                                                const float* __restrict__ Wout,
                                                float* __restrict__ T) {
    const int stage = blockIdx.z;
    const float* A = cbs  + (size_t)stage * NCODE * EMB;
    const float* B = Wout + (size_t)stage * CIN * EMB;
    float* C = T + (size_t)stage * NCODE * CIN;
    __shared__ float As[64][33];
    __shared__ float Bs[64][33];
    const int tid = threadIdx.x;
    const int ty = tid >> 4, tx = tid & 15;
    const int m0 = blockIdx.x * 64;
    const int n0 = blockIdx.y * 64;
    const int lrow = tid >> 5, lcol = tid & 31;
    double acc[4][4];
    #pragma unroll
    for (int i = 0; i < 4; ++i)
        #pragma unroll
        for (int j = 0; j < 4; ++j) acc[i][j] = 0.0;

    for (int k0 = 0; k0 < EMB; k0 += 32) {
        __syncthreads();
        #pragma unroll
        for (int t = 0; t < 8; ++t) {
            int r = lrow + 8 * t;
            As[r][lcol] = A[(size_t)(m0 + r) * EMB + k0 + lcol];
            Bs[r][lcol] = B[(size_t)(n0 + r) * EMB + k0 + lcol];
        }
        __syncthreads();
        #pragma unroll
        for (int k = 0; k < 32; ++k) {
            double a[4], b[4];
            #pragma unroll
            for (int i = 0; i < 4; ++i) a[i] = (double)As[ty * 4 + i][k];
            #pragma unroll
            for (int j = 0; j < 4; ++j) b[j] = (double)Bs[tx * 4 + j][k];
            #pragma unroll
            for (int i = 0; i < 4; ++i)
                #pragma unroll
                for (int j = 0; j < 4; ++j) acc[i][j] += a[i] * b[j];
        }
    }
    #pragma unroll
    for (int i = 0; i < 4; ++i) {
        float4 v = make_float4((float)acc[i][0], (float)acc[i][1],
                               (float)acc[i][2], (float)acc[i][3]);
        *reinterpret_cast<float4*>(&C[(size_t)(m0 + ty * 4 + i) * CIN + n0 + tx * 4]) = v;
    }
}

// ---------------- zi = (z - zq) @ W_in^T via bf16-split MFMA + sum||zi||^2 ----------------
// Wave w handles tokens mw..mw+15; loops 16 n-tiles of 16 channels; K=512 (16 chunks).
__global__ __launch_bounds__(256) void zi_mfma_k(const float* __restrict__ z,
                                                 const float* __restrict__ zq,
                                                 const u16* __restrict__ wh,
                                                 const u16* __restrict__ wl,
                                                 float* __restrict__ zi,
                                                 double* __restrict__ loss_acc,
                                                 int stage0) {
    const int tid = threadIdx.x;
    const int w = tid >> 6;
    const int l = tid & 63;
    const int col = l & 15;
    const int g = l >> 4;
    const int mw = blockIdx.x * 64 + w * 16;

    // A fragments: bf16 hi/lo split of r-row (mw+col), k = kc*32 + g*8 + j
    s16x8 ah[16], al[16];
    {
        const float* zr = z  + (size_t)(mw + col) * CIN + g * 8;
        const float* qr = zq + (size_t)(mw + col) * CIN + g * 8;
        #pragma unroll
        for (int kc = 0; kc < 16; ++kc) {
            float4 f0 = *reinterpret_cast<const float4*>(zr + kc * 32);
            float4 f1 = *reinterpret_cast<const float4*>(zr + kc * 32 + 4);
            float f[8] = {f0.x, f0.y, f0.z, f0.w, f1.x, f1.y, f1.z, f1.w};
            if (!stage0) {
                float4 q0 = *reinterpret_cast<const float4*>(qr + kc * 32);
                float4 q1 = *reinterpret_cast<const float4*>(qr + kc * 32 + 4);
                f[0] -= q0.x; f[1] -= q0.y; f[2] -= q0.z; f[3] -= q0.w;
                f[4] -= q1.x; f[5] -= q1.y; f[6] -= q1.z; f[7] -= q1.w;
            }
            #pragma unroll
            for (int j = 0; j < 8; ++j) {
                u16 h = f2bf(f[j]);
                u16 lo = f2bf(f[j] - bf2f(h));
                ah[kc][j] = (short)h; al[kc][j] = (short)lo;
            }
        }
    }

    double zn = 0.0;
    for (int nt = 0; nt < 16; ++nt) {
        const u16* bh = wh + (size_t)(nt * 16 + col) * CIN + g * 8;
        const u16* bl = wl + (size_t)(nt * 16 + col) * CIN + g * 8;
        f32x4 acc = {0.f, 0.f, 0.f, 0.f};
        #pragma unroll
        for (int kc = 0; kc < 16; ++kc) {
            s16x8 Bh = *reinterpret_cast<const s16x8*>(bh + kc * 32);
            s16x8 Bl = *reinterpret_cast<const s16x8*>(bl + kc * 32);
            acc = __builtin_amdgcn_mfma_f32_16x16x32_bf16(ah[kc], Bh, acc, 0, 0, 0);
            acc = __builtin_amdgcn_mfma_f32_16x16x32_bf16(al[kc], Bh, acc, 0, 0, 0);
            acc = __builtin_amdgcn_mfma_f32_16x16x32_bf16(ah[kc], Bl, acc, 0, 0, 0);
        }
        // C layout: lane holds D[row=g*4+r][col]
        #pragma unroll
        for (int r = 0; r < 4; ++r) {
            zi[(size_t)(mw + g * 4 + r) * EMB + nt * 16 + col] = acc[r];
            zn += (double)acc[r] * (double)acc[r];
        }
    }
    #pragma unroll
    for (int off = 32; off > 0; off >>= 1) zn += __shfl_down(zn, off, 64);
    if (l == 0) atomicAdd(loss_acc, zn);
}

// ---------------- MFMA bf16-split prefilter: best + second-best per token ----------------
__global__ __launch_bounds__(256) void pref_k(const float* __restrict__ zi,
                                              const u16* __restrict__ cbh,
                                              const u16* __restrict__ cbl,
                                              const float* __restrict__ vnorm32,
                                              int* __restrict__ idx,
                                              int* __restrict__ idx_sum,
                                              float* __restrict__ mind,
                                              int* __restrict__ flagged,
                                              int* __restrict__ cnt,
                                              double* __restrict__ loss_acc,
                                              int stage0, int cumprod) {
    __shared__ double loss_s[16];
    const int tid = threadIdx.x;
    const int w = tid >> 6;
    const int l = tid & 63;
    const int col = l & 15;
    const int g = l >> 4;
    const int mw = blockIdx.x * 64 + w * 16;

    s16x8 ah[8], al[8];
    {
        const float* zr = zi + (size_t)(mw + col) * EMB + g * 8;
        #pragma unroll
        for (int kc = 0; kc < 8; ++kc) {
            float4 f0 = *reinterpret_cast<const float4*>(zr + kc * 32);
            float4 f1 = *reinterpret_cast<const float4*>(zr + kc * 32 + 4);
            float f[8] = {f0.x, f0.y, f0.z, f0.w, f1.x, f1.y, f1.z, f1.w};
            #pragma unroll
            for (int j = 0; j < 8; ++j) {
                u16 h = f2bf(f[j]);
                u16 lo = f2bf(f[j] - bf2f(h));
                ah[kc][j] = (short)h;
                al[kc][j] = (short)lo;
            }
        }
    }

    float b1[4] = {1e30f, 1e30f, 1e30f, 1e30f};
    float b2[4] = {1e30f, 1e30f, 1e30f, 1e30f};
    int   i1[4] = {0, 0, 0, 0};

    for (int ct = 0; ct < 64; ++ct) {
        const u16* bh = cbh + (size_t)(ct * 16 + col) * EMB + g * 8;
        const u16* bl = cbl + (size_t)(ct * 16 + col) * EMB + g * 8;
        s16x8 Bh[8], Bl[8];
        #pragma unroll
        for (int kc = 0; kc < 8; ++kc) {
            Bh[kc] = *reinterpret_cast<const s16x8*>(bh + kc * 32);
            Bl[kc] = *reinterpret_cast<const s16x8*>(bl + kc * 32);
        }
        f32x4 acc = {0.f, 0.f, 0.f, 0.f};
        #pragma unroll
        for (int kc = 0; kc < 8; ++kc)
            acc = __builtin_amdgcn_mfma_f32_16x16x32_bf16(ah[kc], Bh[kc], acc, 0, 0, 0);
        #pragma unroll
        for (int kc = 0; kc < 8; ++kc)
            acc = __builtin_amdgcn_mfma_f32_16x16x32_bf16(al[kc], Bh[kc], acc, 0, 0, 0);
        #pragma unroll
        for (int kc = 0; kc < 8; ++kc)
            acc = __builtin_amdgcn_mfma_f32_16x16x32_bf16(ah[kc], Bl[kc], acc, 0, 0, 0);
        const float vn = vnorm32[ct * 16 + col];
        #pragma unroll
        for (int r = 0; r < 4; ++r) {
            float sc = vn - 2.f * acc[r];
            if (sc < b1[r]) { b2[r] = b1[r]; b1[r] = sc; i1[r] = ct * 16 + col; }
            else b2[r] = fminf(b2[r], sc);
        }
    }
    #pragma unroll
    for (int off = 1; off < 16; off <<= 1) {
        #pragma unroll
        for (int r = 0; r < 4; ++r) {
            float ob1 = __shfl_xor(b1[r], off, 64);
            int   oi1 = __shfl_xor(i1[r], off, 64);
            float ob2 = __shfl_xor(b2[r], off, 64);
            if (ob1 < b1[r] || (ob1 == b1[r] && oi1 < i1[r])) {
                b2[r] = fminf(b1[r], ob2); b1[r] = ob1; i1[r] = oi1;
            } else {
                b2[r] = fminf(b2[r], ob1);
            }
        }
    }
    if (col == 0) {
        double lsum = 0.0;
        #pragma unroll
        for (int r = 0; r < 4; ++r) {
            int m = mw + g * 4 + r;
            idx[m] = i1[r];
            if (stage0) idx_sum[m] = i1[r];
            else        idx_sum[m] += i1[r] * cumprod;
            mind[m] = b1[r];                 // score-only part
            lsum += (double)b1[r];
            if (b2[r] - b1[r] < DELTA) {
                int slot = atomicAdd(cnt, 1);
                flagged[slot] = m;
            }
        }
        loss_s[w * 4 + g] = lsum;
    }
    __syncthreads();
    if (tid == 0) {
        double s = 0.0;
        #pragma unroll
        for (int q = 0; q < 16; ++q) s += loss_s[q];
        atomicAdd(loss_acc, s);
    }
}

// ---------------- exact fp64 rescan (recomputes zi in fp64) ----------------
__global__ __launch_bounds__(256) void rescan_k(const float* __restrict__ z,
                                                const float* __restrict__ zqv,
                                                const float* __restrict__ Win,
                                                const float* __restrict__ cb,
                                                const double* __restrict__ vnorm64,
                                                const int* __restrict__ flagged,
                                                const int* __restrict__ cnt,
                                                int* __restrict__ idx,
                                                int* __restrict__ idx_sum,
                                                float* __restrict__ mind,
                                                double* __restrict__ loss_acc,
                                                int cumprod, int stage0) {
    __shared__ double r64[CIN];
    __shared__ double zi64[EMB];
    __shared__ double sred[256];
    __shared__ int ired[256];
    int n = *cnt;
    for (int j = blockIdx.x; j < n; j += gridDim.x) {
        int m = flagged[j];
        __syncthreads();
        for (int k = threadIdx.x; k < CIN; k += 256) {
            float rv = z[(size_t)m * CIN + k];
            if (!stage0) rv -= zqv[(size_t)m * CIN + k];   // fp32 subtract (matches ref)
            r64[k] = (double)rv;
        }
        __syncthreads();
        {
            const float* wr = Win + (size_t)threadIdx.x * CIN;
            double s = 0.0;
            for (int k = 0; k < CIN; ++k) s += r64[k] * (double)wr[k];
            zi64[threadIdx.x] = s;
        }
        __syncthreads();
        double best = 1e300; int bi = 0;
        for (int jj = 0; jj < 4; ++jj) {
            int c = threadIdx.x * 4 + jj;   // ascending within thread
            const float* row = cb + (size_t)c * EMB;
            double d = 0.0;
            for (int k = 0; k < EMB; ++k) d += zi64[k] * (double)row[k];
            double sc = vnorm64[c] - 2.0 * d;
            if (sc < best) { best = sc; bi = c; }
        }
        sred[threadIdx.x] = best; ired[threadIdx.x] = bi;
        __syncthreads();
        for (int off = 128; off > 0; off >>= 1) {
            if (threadIdx.x < off) {
                double ob = sred[threadIdx.x + off]; int oi = ired[threadIdx.x + off];
                if (ob < sred[threadIdx.x] ||
                    (ob == sred[threadIdx.x] && oi < ired[threadIdx.x])) {
                    sred[threadIdx.x] = ob; ired[threadIdx.x] = oi;
                }
            }
            __syncthreads();
        }
        if (threadIdx.x == 0) {
            int newI = ired[0], oldI = idx[m];
            if (newI != oldI) { idx[m] = newI; idx_sum[m] += (newI - oldI) * cumprod; }
            atomicAdd(loss_acc, sred[0] - (double)mind[m]);
            mind[m] = (float)sred[0];
        }
        __syncthreads();
    }
}

// ---------------- zq (+)= T[idx]  (row gather) ----------------
__global__ __launch_bounds__(256) void gather_k(const float* __restrict__ T,
                                                const int* __restrict__ idx,
                                                float* __restrict__ zq, int stage0) {
    int m = blockIdx.x * 16 + (threadIdx.x >> 4);
    int q = threadIdx.x & 15;
    const float* src = T + (size_t)idx[m] * CIN;
    float* dst = zq + (size_t)m * CIN;
    #pragma unroll
    for (int it = 0; it < 8; ++it) {
        int off = it * 64 + q * 4;
        float4 t = *reinterpret_cast<const float4*>(src + off);
        if (!stage0) {
            float4 o = *reinterpret_cast<const float4*>(dst + off);
            t.x += o.x; t.y += o.y; t.z += o.z; t.w += o.w;
        }
        *reinterpret_cast<float4*>(dst + off) = t;
    }
}

// ---------------- sum (z - z_q)^2 ----------------
__global__ __launch_bounds__(256) void sqred_k(const float* __restrict__ z,
                                               const float* __restrict__ zq,
                                               double* __restrict__ acc) {
    __shared__ double red[256];
    int i0 = blockIdx.x * 256 + threadIdx.x;
    int stride = gridDim.x * 256;
    double s = 0.0;
    for (int i = i0; i < MTOK * CIN; i += stride) {
        double d = (double)z[i] - (double)zq[i];
        s += d * d;
    }
    red[threadIdx.x] = s;
    __syncthreads();
    for (int off = 128; off > 0; off >>= 1) {
        if (threadIdx.x < off) red[threadIdx.x] += red[threadIdx.x + off];
        __syncthreads();
    }
    if (threadIdx.x == 0) atomicAdd(acc + 1, red[0]);
}

// ---------------- finalize ----------------
__global__ void final_k(const int* __restrict__ idx_sum,
                        const double* __restrict__ loss_acc,
                        float* __restrict__ out) {
    int i = blockIdx.x * blockDim.x + threadIdx.x;
    if (i < MTOK) out[MTOK * CIN + i] = (float)idx_sum[i];
    if (i == 0) {
        double loss = 2.0 * loss_acc[0] / (3.0 * (double)MTOK * (double)EMB)
                    + loss_acc[1] / ((double)MTOK * (double)CIN);
        out[MTOK * CIN + MTOK] = (float)loss;
    }
}

extern "C" void kernel_launch(void* const* d_in, const int* in_sizes, int n_in,
                              void* d_out, int out_size, void* d_ws, size_t ws_size,
                              hipStream_t stream) {
    const float* z     = (const float*)d_in[0];
    const float* W_in  = (const float*)d_in[1];
    const float* W_out = (const float*)d_in[2];
    const float* cbs   = (const float*)d_in[3];
    float* out = (float*)d_out;
    char* ws = (char*)d_ws;

    // ws layout (16B-aligned)
    double* vnorm64  = (double*)ws;                               // 24576
    double* loss_acc = (double*)(ws + 24576);                     // 16
    float*  vnorm32  = (float*)(ws + 24592);                      // 12288
    int*    cnt      = (int*)(ws + 36880);                        // 16
    u16*    cbh      = (u16*)(ws + 36896);                        // 1572864
    u16*    cbl      = (u16*)(ws + 1609760);                      // 1572864
    u16*    wh       = (u16*)(ws + 3182624);                      // 786432
    u16*    wl       = (u16*)(ws + 3969056);                      // 786432
    float*  T        = (float*)(ws + 4755488);                    // 6291456
    float*  zi       = (float*)(ws + 11046944);                   // 33554432
    char*   p        = ws + 11046944 + (size_t)MTOK * EMB * 4;
    int*    idx      = (int*)p;                                   // 131072
    int*    idx_sum  = (int*)(p + 131072);                        // 131072
    int*    flagged  = (int*)(p + 262144);                        // 131072
    float*  mind     = (float*)(p + 393216);                      // 131072

    float* zq = out;  // z_q lives in d_out[0 .. MTOK*CIN)

    init_k<<<dim3(1), dim3(1), 0, stream>>>(loss_acc, cnt);
    prep_cb_k<<<dim3(VQ * NCODE), dim3(64), 0, stream>>>(cbs, vnorm64, vnorm32, cbh, cbl);
    prep_w_k<<<dim3(VQ * EMB * CIN / 256), dim3(256), 0, stream>>>(W_in, wh, wl);
    prep_T_k<<<dim3(NCODE / 64, CIN / 64, VQ), dim3(256), 0, stream>>>(cbs, W_out, T);

    const int cumprod[VQ] = {1, 1024, 1024 * 1024};
    for (int i = 0; i < VQ; ++i) {
        const float* cb = cbs + (size_t)i * NCODE * EMB;
        zi_mfma_k<<<dim3(MTOK / 64), dim3(256), 0, stream>>>(
            z, zq, wh + (size_t)i * EMB * CIN, wl + (size_t)i * EMB * CIN,
            zi, loss_acc, i == 0 ? 1 : 0);
        pref_k<<<dim3(MTOK / 64), dim3(256), 0, stream>>>(
            zi, cbh + (size_t)i * NCODE * EMB, cbl + (size_t)i * NCODE * EMB,
            vnorm32 + i * NCODE, idx, idx_sum, mind, flagged, cnt + i, loss_acc,
            i == 0 ? 1 : 0, cumprod[i]);
        rescan_k<<<dim3(512), dim3(256), 0, stream>>>(
            z, zq, W_in + (size_t)i * EMB * CIN, cb, vnorm64 + i * NCODE,
            flagged, cnt + i, idx, idx_sum, mind, loss_acc, cumprod[i],
            i == 0 ? 1 : 0);
        gather_k<<<dim3(MTOK / 16), dim3(256), 0, stream>>>(
            T + (size_t)i * NCODE * CIN, idx, zq, i == 0 ? 1 : 0);
    }
    sqred_k<<<dim3(2048), dim3(256), 0, stream>>>(z, zq, loss_acc);
    final_k<<<dim3(MTOK / 256), dim3(256), 0, stream>>>(idx_sum, loss_acc, out);
}

// Round 5
// 1702.890 us; speedup vs baseline: 2.6631x; 1.0765x over previous
//
#include <hip/hip_runtime.h>

#define MTOK 32768   // 8*4096 tokens
#define CIN  512     // in_ch
#define EMB  256     // emb_ch
#define NCODE 1024
#define VQ   3
#define DELTA 2e-3f  // certified margin; worst-case approx score-diff error ~3e-4

typedef short s16x8 __attribute__((ext_vector_type(8)));
typedef float f32x4 __attribute__((ext_vector_type(4)));
typedef unsigned short u16;

static __device__ __forceinline__ u16 f2bf(float x) {
    unsigned int u = __float_as_uint(x);
    u += 0x7FFF + ((u >> 16) & 1);          // RNE
    return (u16)(u >> 16);
}
static __device__ __forceinline__ float bf2f(u16 h) {
    return __uint_as_float(((unsigned int)h) << 16);
}

// ---------------- init ----------------
__global__ void init_k(double* loss_acc, int* cnt) {
    loss_acc[0] = 0.0;  // sum of min-dists (znorm parts + score parts)
    loss_acc[1] = 0.0;  // sum (z - z_q)^2
    cnt[0] = 0; cnt[1] = 0; cnt[2] = 0;
}

// ---------------- codebook prep: ||v||^2 (fp64/fp32) + bf16 hi/lo split ----------------
__global__ __launch_bounds__(64) void prep_cb_k(const float* __restrict__ cbs,
                                                double* __restrict__ vnorm64,
                                                float* __restrict__ vnorm32,
                                                u16* __restrict__ cbh,
                                                u16* __restrict__ cbl) {
    int s = blockIdx.x;                       // 0 .. 3*NCODE-1
    const float* row = cbs + (size_t)s * EMB;
    double acc = 0.0;
    for (int k = threadIdx.x; k < EMB; k += 64) {
        float v = row[k];
        double vd = (double)v; acc += vd * vd;
        u16 h = f2bf(v);
        u16 l = f2bf(v - bf2f(h));
        cbh[(size_t)s * EMB + k] = h;
        cbl[(size_t)s * EMB + k] = l;
    }
    #pragma unroll
    for (int off = 32; off > 0; off >>= 1) acc += __shfl_down(acc, off, 64);
    if (threadIdx.x == 0) { vnorm64[s] = acc; vnorm32[s] = (float)acc; }
}

// ---------------- W_in bf16 hi/lo split ----------------
__global__ __launch_bounds__(256) void prep_w_k(const float* __restrict__ W_in,
                                                u16* __restrict__ wh,
                                                u16* __restrict__ wl) {
    int i = blockIdx.x * 256 + threadIdx.x;   // < VQ*EMB*CIN
    float v = W_in[i];
    u16 h = f2bf(v);
    wh[i] = h;
    wl[i] = f2bf(v - bf2f(h));
}

// ---------------- T[s] = cb[s] @ W_out[s]^T  (fp64 acc, fp32 store) ----------------
__global__ __launch_bounds__(256) void prep_T_k(const float* __restrict__ cbs,
                                                const float* __restrict__ Wout,
                                                float* __restrict__ T) {
    const int stage = blockIdx.z;
    const float* A = cbs  + (size_t)stage * NCODE * EMB;
    const float* B = Wout + (size_t)stage * CIN * EMB;
    float* C = T + (size_t)stage * NCODE * CIN;
    __shared__ float As[64][33];
    __shared__ float Bs[64][33];
    const int tid = threadIdx.x;
    const int ty = tid >> 4, tx = tid & 15;
    const int m0 = blockIdx.x * 64;
    const int n0 = blockIdx.y * 64;
    const int lrow = tid >> 5, lcol = tid & 31;
    double acc[4][4];
    #pragma unroll
    for (int i = 0; i < 4; ++i)
        #pragma unroll
        for (int j = 0; j < 4; ++j) acc[i][j] = 0.0;

    for (int k0 = 0; k0 < EMB; k0 += 32) {
        __syncthreads();
        #pragma unroll
        for (int t = 0; t < 8; ++t) {
            int r = lrow + 8 * t;
            As[r][lcol] = A[(size_t)(m0 + r) * EMB + k0 + lcol];
            Bs[r][lcol] = B[(size_t)(n0 + r) * EMB + k0 + lcol];
        }
        __syncthreads();
        #pragma unroll
        for (int k = 0; k < 32; ++k) {
            double a[4], b[4];
            #pragma unroll
            for (int i = 0; i < 4; ++i) a[i] = (double)As[ty * 4 + i][k];
            #pragma unroll
            for (int j = 0; j < 4; ++j) b[j] = (double)Bs[tx * 4 + j][k];
            #pragma unroll
            for (int i = 0; i < 4; ++i)
                #pragma unroll
                for (int j = 0; j < 4; ++j) acc[i][j] += a[i] * b[j];
        }
    }
    #pragma unroll
    for (int i = 0; i < 4; ++i) {
        float4 v = make_float4((float)acc[i][0], (float)acc[i][1],
                               (float)acc[i][2], (float)acc[i][3]);
        *reinterpret_cast<float4*>(&C[(size_t)(m0 + ty * 4 + i) * CIN + n0 + tx * 4]) = v;
    }
}

// ---------------- zi = (z - zq) @ W_in^T via bf16-split MFMA + sum||zi||^2 ----------------
// 8-slot rolling B-window (prefetch distance = 8 chunk-pairs), 3 indep acc chains.
__global__ __launch_bounds__(256, 2) void zi_mfma_k(const float* __restrict__ z,
                                                    const float* __restrict__ zq,
                                                    const u16* __restrict__ wh,
                                                    const u16* __restrict__ wl,
                                                    float* __restrict__ zi,
                                                    double* __restrict__ loss_acc,
                                                    int stage0) {
    const int tid = threadIdx.x;
    const int w = tid >> 6;
    const int l = tid & 63;
    const int col = l & 15;
    const int g = l >> 4;
    const int mw = blockIdx.x * 64 + w * 16;

    // A fragments: bf16 hi/lo split of r-row (mw+col), k = kc*32 + g*8 + j
    s16x8 ah[16], al[16];
    {
        const float* zr = z  + (size_t)(mw + col) * CIN + g * 8;
        const float* qr = zq + (size_t)(mw + col) * CIN + g * 8;
        #pragma unroll
        for (int kc = 0; kc < 16; ++kc) {
            float4 f0 = *reinterpret_cast<const float4*>(zr + kc * 32);
            float4 f1 = *reinterpret_cast<const float4*>(zr + kc * 32 + 4);
            float f[8] = {f0.x, f0.y, f0.z, f0.w, f1.x, f1.y, f1.z, f1.w};
            if (!stage0) {
                float4 q0 = *reinterpret_cast<const float4*>(qr + kc * 32);
                float4 q1 = *reinterpret_cast<const float4*>(qr + kc * 32 + 4);
                f[0] -= q0.x; f[1] -= q0.y; f[2] -= q0.z; f[3] -= q0.w;
                f[4] -= q1.x; f[5] -= q1.y; f[6] -= q1.z; f[7] -= q1.w;
            }
            #pragma unroll
            for (int j = 0; j < 8; ++j) {
                u16 h = f2bf(f[j]);
                u16 lo = f2bf(f[j] - bf2f(h));
                ah[kc][j] = (short)h; al[kc][j] = (short)lo;
            }
        }
    }

    const u16* ph = wh + (size_t)col * CIN + g * 8;
    const u16* pl = wl + (size_t)col * CIN + g * 8;

    // prologue: chunks 0..7 of nt=0
    s16x8 Sh[8], Sl[8];
    #pragma unroll
    for (int kc = 0; kc < 8; ++kc) {
        Sh[kc] = *reinterpret_cast<const s16x8*>(ph + kc * 32);
        Sl[kc] = *reinterpret_cast<const s16x8*>(pl + kc * 32);
    }

    double zn = 0.0;
    for (int nt = 0; nt < 16; ++nt) {
        const u16* bh = ph + (size_t)nt * (16 * CIN);
        const u16* bl = pl + (size_t)nt * (16 * CIN);
        f32x4 a0 = {0.f, 0.f, 0.f, 0.f};
        f32x4 a1 = {0.f, 0.f, 0.f, 0.f};
        f32x4 a2 = {0.f, 0.f, 0.f, 0.f};
        #pragma unroll
        for (int kc = 0; kc < 16; ++kc) {
            const int s = kc & 7;
            a0 = __builtin_amdgcn_mfma_f32_16x16x32_bf16(ah[kc], Sh[s], a0, 0, 0, 0);
            a1 = __builtin_amdgcn_mfma_f32_16x16x32_bf16(al[kc], Sh[s], a1, 0, 0, 0);
            a2 = __builtin_amdgcn_mfma_f32_16x16x32_bf16(ah[kc], Sl[s], a2, 0, 0, 0);
            if (kc < 8) {                      // refill: chunks 8..15 of this nt
                Sh[s] = *reinterpret_cast<const s16x8*>(bh + (kc + 8) * 32);
                Sl[s] = *reinterpret_cast<const s16x8*>(bl + (kc + 8) * 32);
            } else if (nt < 15) {              // refill: chunks 0..7 of next nt
                Sh[s] = *reinterpret_cast<const s16x8*>(bh + 16 * CIN + (kc - 8) * 32);
                Sl[s] = *reinterpret_cast<const s16x8*>(bl + 16 * CIN + (kc - 8) * 32);
            }
        }
        #pragma unroll
        for (int r = 0; r < 4; ++r) {
            float v = a0[r] + a1[r] + a2[r];
            zi[(size_t)(mw + g * 4 + r) * EMB + nt * 16 + col] = v;
            zn += (double)v * (double)v;
        }
    }
    #pragma unroll
    for (int off = 32; off > 0; off >>= 1) zn += __shfl_down(zn, off, 64);
    if (l == 0) atomicAdd(loss_acc, zn);
}

// ---------------- MFMA bf16-split prefilter: best + second-best per token ----------------
// X/Y ct-level double buffer, 3 indep acc chains.
#define SCORE_BLOCK(Bh, Bl, CT) do {                                              \
    f32x4 a0 = {0.f, 0.f, 0.f, 0.f};                                              \
    f32x4 a1 = {0.f, 0.f, 0.f, 0.f};                                              \
    f32x4 a2 = {0.f, 0.f, 0.f, 0.f};                                              \
    _Pragma("unroll")                                                              \
    for (int kc = 0; kc < 8; ++kc) {                                               \
        a0 = __builtin_amdgcn_mfma_f32_16x16x32_bf16(ah[kc], Bh[kc], a0, 0, 0, 0); \
        a1 = __builtin_amdgcn_mfma_f32_16x16x32_bf16(al[kc], Bh[kc], a1, 0, 0, 0); \
        a2 = __builtin_amdgcn_mfma_f32_16x16x32_bf16(ah[kc], Bl[kc], a2, 0, 0, 0); \
    }                                                                              \
    const float vn = vnorm32[(CT) * 16 + col];                                     \
    _Pragma("unroll")                                                              \
    for (int r = 0; r < 4; ++r) {                                                  \
        float sc = vn - 2.f * (a0[r] + a1[r] + a2[r]);                             \
        if (sc < b1[r]) { b2[r] = b1[r]; b1[r] = sc; i1[r] = (CT) * 16 + col; }    \
        else b2[r] = fminf(b2[r], sc);                                             \
    }                                                                              \
} while (0)

__global__ __launch_bounds__(256, 2) void pref_k(const float* __restrict__ zi,
                                                 const u16* __restrict__ cbh,
                                                 const u16* __restrict__ cbl,
                                                 const float* __restrict__ vnorm32,
                                                 int* __restrict__ idx,
                                                 int* __restrict__ idx_sum,
                                                 float* __restrict__ mind,
                                                 int* __restrict__ flagged,
                                                 int* __restrict__ cnt,
                                                 double* __restrict__ loss_acc,
                                                 int stage0, int cumprod) {
    __shared__ double loss_s[16];
    const int tid = threadIdx.x;
    const int w = tid >> 6;
    const int l = tid & 63;
    const int col = l & 15;
    const int g = l >> 4;
    const int mw = blockIdx.x * 64 + w * 16;

    s16x8 ah[8], al[8];
    {
        const float* zr = zi + (size_t)(mw + col) * EMB + g * 8;
        #pragma unroll
        for (int kc = 0; kc < 8; ++kc) {
            float4 f0 = *reinterpret_cast<const float4*>(zr + kc * 32);
            float4 f1 = *reinterpret_cast<const float4*>(zr + kc * 32 + 4);
            float f[8] = {f0.x, f0.y, f0.z, f0.w, f1.x, f1.y, f1.z, f1.w};
            #pragma unroll
            for (int j = 0; j < 8; ++j) {
                u16 h = f2bf(f[j]);
                u16 lo = f2bf(f[j] - bf2f(h));
                ah[kc][j] = (short)h;
                al[kc][j] = (short)lo;
            }
        }
    }

    float b1[4] = {1e30f, 1e30f, 1e30f, 1e30f};
    float b2[4] = {1e30f, 1e30f, 1e30f, 1e30f};
    int   i1[4] = {0, 0, 0, 0};

    const u16* ph = cbh + (size_t)col * EMB + g * 8;
    const u16* pl = cbl + (size_t)col * EMB + g * 8;

    s16x8 Xh[8], Xl[8], Yh[8], Yl[8];
    #pragma unroll
    for (int kc = 0; kc < 8; ++kc) {                    // prologue: ct=0 into X
        Xh[kc] = *reinterpret_cast<const s16x8*>(ph + kc * 32);
        Xl[kc] = *reinterpret_cast<const s16x8*>(pl + kc * 32);
    }

    for (int ct = 0; ct < 64; ct += 2) {
        {   // load Y <- ct+1
            const u16* qh = ph + (size_t)(ct + 1) * (16 * EMB);
            const u16* ql = pl + (size_t)(ct + 1) * (16 * EMB);
            #pragma unroll
            for (int kc = 0; kc < 8; ++kc) {
                Yh[kc] = *reinterpret_cast<const s16x8*>(qh + kc * 32);
                Yl[kc] = *reinterpret_cast<const s16x8*>(ql + kc * 32);
            }
        }
        SCORE_BLOCK(Xh, Xl, ct);
        if (ct + 2 < 64) {  // load X <- ct+2
            const u16* qh = ph + (size_t)(ct + 2) * (16 * EMB);
            const u16* ql = pl + (size_t)(ct + 2) * (16 * EMB);
            #pragma unroll
            for (int kc = 0; kc < 8; ++kc) {
                Xh[kc] = *reinterpret_cast<const s16x8*>(qh + kc * 32);
                Xl[kc] = *reinterpret_cast<const s16x8*>(ql + kc * 32);
            }
        }
        SCORE_BLOCK(Yh, Yl, ct + 1);
    }

    #pragma unroll
    for (int off = 1; off < 16; off <<= 1) {
        #pragma unroll
        for (int r = 0; r < 4; ++r) {
            float ob1 = __shfl_xor(b1[r], off, 64);
            int   oi1 = __shfl_xor(i1[r], off, 64);
            float ob2 = __shfl_xor(b2[r], off, 64);
            if (ob1 < b1[r] || (ob1 == b1[r] && oi1 < i1[r])) {
                b2[r] = fminf(b1[r], ob2); b1[r] = ob1; i1[r] = oi1;
            } else {
                b2[r] = fminf(b2[r], ob1);
            }
        }
    }
    if (col == 0) {
        double lsum = 0.0;
        #pragma unroll
        for (int r = 0; r < 4; ++r) {
            int m = mw + g * 4 + r;
            idx[m] = i1[r];
            if (stage0) idx_sum[m] = i1[r];
            else        idx_sum[m] += i1[r] * cumprod;
            mind[m] = b1[r];                 // score-only part
            lsum += (double)b1[r];
            if (b2[r] - b1[r] < DELTA) {
                int slot = atomicAdd(cnt, 1);
                flagged[slot] = m;
            }
        }
        loss_s[w * 4 + g] = lsum;
    }
    __syncthreads();
    if (tid == 0) {
        double s = 0.0;
        #pragma unroll
        for (int q = 0; q < 16; ++q) s += loss_s[q];
        atomicAdd(loss_acc, s);
    }
}

// ---------------- exact fp64 rescan (recomputes zi in fp64) ----------------
__global__ __launch_bounds__(256) void rescan_k(const float* __restrict__ z,
                                                const float* __restrict__ zqv,
                                                const float* __restrict__ Win,
                                                const float* __restrict__ cb,
                                                const double* __restrict__ vnorm64,
                                                const int* __restrict__ flagged,
                                                const int* __restrict__ cnt,
                                                int* __restrict__ idx,
                                                int* __restrict__ idx_sum,
                                                float* __restrict__ mind,
                                                double* __restrict__ loss_acc,
                                                int cumprod, int stage0) {
    __shared__ double r64[CIN];
    __shared__ double zi64[EMB];
    __shared__ double sred[256];
    __shared__ int ired[256];
    int n = *cnt;
    for (int j = blockIdx.x; j < n; j += gridDim.x) {
        int m = flagged[j];
        __syncthreads();
        for (int k = threadIdx.x; k < CIN; k += 256) {
            float rv = z[(size_t)m * CIN + k];
            if (!stage0) rv -= zqv[(size_t)m * CIN + k];   // fp32 subtract (matches ref)
            r64[k] = (double)rv;
        }
        __syncthreads();
        {
            const float* wr = Win + (size_t)threadIdx.x * CIN;
            double s = 0.0;
            for (int k = 0; k < CIN; ++k) s += r64[k] * (double)wr[k];
            zi64[threadIdx.x] = s;
        }
        __syncthreads();
        double best = 1e300; int bi = 0;
        for (int jj = 0; jj < 4; ++jj) {
            int c = threadIdx.x * 4 + jj;   // ascending within thread
            const float* row = cb + (size_t)c * EMB;
            double d = 0.0;
            for (int k = 0; k < EMB; ++k) d += zi64[k] * (double)row[k];
            double sc = vnorm64[c] - 2.0 * d;
            if (sc < best) { best = sc; bi = c; }
        }
        sred[threadIdx.x] = best; ired[threadIdx.x] = bi;
        __syncthreads();
        for (int off = 128; off > 0; off >>= 1) {
            if (threadIdx.x < off) {
                double ob = sred[threadIdx.x + off]; int oi = ired[threadIdx.x + off];
                if (ob < sred[threadIdx.x] ||
                    (ob == sred[threadIdx.x] && oi < ired[threadIdx.x])) {
                    sred[threadIdx.x] = ob; ired[threadIdx.x] = oi;
                }
            }
            __syncthreads();
        }
        if (threadIdx.x == 0) {
            int newI = ired[0], oldI = idx[m];
            if (newI != oldI) { idx[m] = newI; idx_sum[m] += (newI - oldI) * cumprod; }
            atomicAdd(loss_acc, sred[0] - (double)mind[m]);
            mind[m] = (float)sred[0];
        }
        __syncthreads();
    }
}

// ---------------- zq (+)= T[idx]  (row gather); last stage also sums (z - zq)^2 ----------------
__global__ __launch_bounds__(256) void gather_k(const float* __restrict__ T,
                                                const int* __restrict__ idx,
                                                const float* __restrict__ z,
                                                float* __restrict__ zq,
                                                int stage0, int last,
                                                double* __restrict__ loss_acc) {
    __shared__ double red[256];
    int m = blockIdx.x * 16 + (threadIdx.x >> 4);
    int q = threadIdx.x & 15;
    const float* src = T + (size_t)idx[m] * CIN;
    float* dst = zq + (size_t)m * CIN;
    double s = 0.0;
    #pragma unroll
    for (int it = 0; it < 8; ++it) {
        int off = it * 64 + q * 4;
        float4 t = *reinterpret_cast<const float4*>(src + off);
        if (!stage0) {
            float4 o = *reinterpret_cast<const float4*>(dst + off);
            t.x += o.x; t.y += o.y; t.z += o.z; t.w += o.w;
        }
        *reinterpret_cast<float4*>(dst + off) = t;
        if (last) {
            float4 zv = *reinterpret_cast<const float4*>(z + (size_t)m * CIN + off);
            double d0 = (double)zv.x - (double)t.x;
            double d1 = (double)zv.y - (double)t.y;
            double d2 = (double)zv.z - (double)t.z;
            double d3 = (double)zv.w - (double)t.w;
            s += d0 * d0 + d1 * d1 + d2 * d2 + d3 * d3;
        }
    }
    if (last) {
        red[threadIdx.x] = s;
        __syncthreads();
        for (int off = 128; off > 0; off >>= 1) {
            if (threadIdx.x < off) red[threadIdx.x] += red[threadIdx.x + off];
            __syncthreads();
        }
        if (threadIdx.x == 0) atomicAdd(loss_acc + 1, red[0]);
    }
}

// ---------------- finalize ----------------
__global__ void final_k(const int* __restrict__ idx_sum,
                        const double* __restrict__ loss_acc,
                        float* __restrict__ out) {
    int i = blockIdx.x * blockDim.x + threadIdx.x;
    if (i < MTOK) out[MTOK * CIN + i] = (float)idx_sum[i];
    if (i == 0) {
        double loss = 2.0 * loss_acc[0] / (3.0 * (double)MTOK * (double)EMB)
                    + loss_acc[1] / ((double)MTOK * (double)CIN);
        out[MTOK * CIN + MTOK] = (float)loss;
    }
}

extern "C" void kernel_launch(void* const* d_in, const int* in_sizes, int n_in,
                              void* d_out, int out_size, void* d_ws, size_t ws_size,
                              hipStream_t stream) {
    const float* z     = (const float*)d_in[0];
    const float* W_in  = (const float*)d_in[1];
    const float* W_out = (const float*)d_in[2];
    const float* cbs   = (const float*)d_in[3];
    float* out = (float*)d_out;
    char* ws = (char*)d_ws;

    // ws layout (16B-aligned)
    double* vnorm64  = (double*)ws;                               // 24576
    double* loss_acc = (double*)(ws + 24576);                     // 16
    float*  vnorm32  = (float*)(ws + 24592);                      // 12288
    int*    cnt      = (int*)(ws + 36880);                        // 16
    u16*    cbh      = (u16*)(ws + 36896);                        // 1572864
    u16*    cbl      = (u16*)(ws + 1609760);                      // 1572864
    u16*    wh       = (u16*)(ws + 3182624);                      // 786432
    u16*    wl       = (u16*)(ws + 3969056);                      // 786432
    float*  T        = (float*)(ws + 4755488);                    // 6291456
    float*  zi       = (float*)(ws + 11046944);                   // 33554432
    char*   p        = ws + 11046944 + (size_t)MTOK * EMB * 4;
    int*    idx      = (int*)p;                                   // 131072
    int*    idx_sum  = (int*)(p + 131072);                        // 131072
    int*    flagged  = (int*)(p + 262144);                        // 131072
    float*  mind     = (float*)(p + 393216);                      // 131072

    float* zq = out;  // z_q lives in d_out[0 .. MTOK*CIN)

    init_k<<<dim3(1), dim3(1), 0, stream>>>(loss_acc, cnt);
    prep_cb_k<<<dim3(VQ * NCODE), dim3(64), 0, stream>>>(cbs, vnorm64, vnorm32, cbh, cbl);
    prep_w_k<<<dim3(VQ * EMB * CIN / 256), dim3(256), 0, stream>>>(W_in, wh, wl);
    prep_T_k<<<dim3(NCODE / 64, CIN / 64, VQ), dim3(256), 0, stream>>>(cbs, W_out, T);

    const int cumprod[VQ] = {1, 1024, 1024 * 1024};
    for (int i = 0; i < VQ; ++i) {
        const float* cb = cbs + (size_t)i * NCODE * EMB;
        zi_mfma_k<<<dim3(MTOK / 64), dim3(256), 0, stream>>>(
            z, zq, wh + (size_t)i * EMB * CIN, wl + (size_t)i * EMB * CIN,
            zi, loss_acc, i == 0 ? 1 : 0);
        pref_k<<<dim3(MTOK / 64), dim3(256), 0, stream>>>(
            zi, cbh + (size_t)i * NCODE * EMB, cbl + (size_t)i * NCODE * EMB,
            vnorm32 + i * NCODE, idx, idx_sum, mind, flagged, cnt + i, loss_acc,
            i == 0 ? 1 : 0, cumprod[i]);
        rescan_k<<<dim3(512), dim3(256), 0, stream>>>(
            z, zq, W_in + (size_t)i * EMB * CIN, cb, vnorm64 + i * NCODE,
            flagged, cnt + i, idx, idx_sum, mind, loss_acc, cumprod[i],
            i == 0 ? 1 : 0);
        gather_k<<<dim3(MTOK / 16), dim3(256), 0, stream>>>(
            T + (size_t)i * NCODE * CIN, idx, z, zq, i == 0 ? 1 : 0,
            i == VQ - 1 ? 1 : 0, loss_acc);
    }
    final_k<<<dim3(MTOK / 256), dim3(256), 0, stream>>>(idx_sum, loss_acc, out);
}

// Round 6
// 951.123 us; speedup vs baseline: 4.7679x; 1.7904x over previous
//
#include <hip/hip_runtime.h>

#define MTOK 32768   // 8*4096 tokens
#define CIN  512     // in_ch
#define EMB  256     // emb_ch
#define NCODE 1024
#define VQ   3
#define DELTA 2e-3f  // certified margin; worst-case approx score-diff error ~3e-4

typedef short s16x8 __attribute__((ext_vector_type(8)));
typedef float f32x4 __attribute__((ext_vector_type(4)));
typedef unsigned short u16;

static __device__ __forceinline__ u16 f2bf(float x) {
    unsigned int u = __float_as_uint(x);
    u += 0x7FFF + ((u >> 16) & 1);          // RNE
    return (u16)(u >> 16);
}
static __device__ __forceinline__ float bf2f(u16 h) {
    return __uint_as_float(((unsigned int)h) << 16);
}

// ---------------- init ----------------
__global__ void init_k(double* loss_acc, int* cnt) {
    loss_acc[0] = 0.0;  // sum of min-dists (znorm parts + score parts)
    loss_acc[1] = 0.0;  // sum (z - z_q)^2
    cnt[0] = 0; cnt[1] = 0; cnt[2] = 0;
}

// ---------------- codebook prep: ||v||^2 (fp64/fp32) + bf16 hi/lo split ----------------
__global__ __launch_bounds__(64) void prep_cb_k(const float* __restrict__ cbs,
                                                double* __restrict__ vnorm64,
                                                float* __restrict__ vnorm32,
                                                u16* __restrict__ cbh,
                                                u16* __restrict__ cbl) {
    int s = blockIdx.x;                       // 0 .. 3*NCODE-1
    const float* row = cbs + (size_t)s * EMB;
    double acc = 0.0;
    for (int k = threadIdx.x; k < EMB; k += 64) {
        float v = row[k];
        double vd = (double)v; acc += vd * vd;
        u16 h = f2bf(v);
        u16 l = f2bf(v - bf2f(h));
        cbh[(size_t)s * EMB + k] = h;
        cbl[(size_t)s * EMB + k] = l;
    }
    #pragma unroll
    for (int off = 32; off > 0; off >>= 1) acc += __shfl_down(acc, off, 64);
    if (threadIdx.x == 0) { vnorm64[s] = acc; vnorm32[s] = (float)acc; }
}

// ---------------- W_in bf16 hi/lo split ----------------
__global__ __launch_bounds__(256) void prep_w_k(const float* __restrict__ W_in,
                                                u16* __restrict__ wh,
                                                u16* __restrict__ wl) {
    int i = blockIdx.x * 256 + threadIdx.x;   // < VQ*EMB*CIN
    float v = W_in[i];
    u16 h = f2bf(v);
    wh[i] = h;
    wl[i] = f2bf(v - bf2f(h));
}

// ---------------- T[s] = cb[s] @ W_out[s]^T  (fp64 acc, fp32 store) ----------------
__global__ __launch_bounds__(256) void prep_T_k(const float* __restrict__ cbs,
                                                const float* __restrict__ Wout,
                                                float* __restrict__ T) {
    const int stage = blockIdx.z;
    const float* A = cbs  + (size_t)stage * NCODE * EMB;
    const float* B = Wout + (size_t)stage * CIN * EMB;
    float* C = T + (size_t)stage * NCODE * CIN;
    __shared__ float As[64][33];
    __shared__ float Bs[64][33];
    const int tid = threadIdx.x;
    const int ty = tid >> 4, tx = tid & 15;
    const int m0 = blockIdx.x * 64;
    const int n0 = blockIdx.y * 64;
    const int lrow = tid >> 5, lcol = tid & 31;
    double acc[4][4];
    #pragma unroll
    for (int i = 0; i < 4; ++i)
        #pragma unroll
        for (int j = 0; j < 4; ++j) acc[i][j] = 0.0;

    for (int k0 = 0; k0 < EMB; k0 += 32) {
        __syncthreads();
        #pragma unroll
        for (int t = 0; t < 8; ++t) {
            int r = lrow + 8 * t;
            As[r][lcol] = A[(size_t)(m0 + r) * EMB + k0 + lcol];
            Bs[r][lcol] = B[(size_t)(n0 + r) * EMB + k0 + lcol];
        }
        __syncthreads();
        #pragma unroll
        for (int k = 0; k < 32; ++k) {
            double a[4], b[4];
            #pragma unroll
            for (int i = 0; i < 4; ++i) a[i] = (double)As[ty * 4 + i][k];
            #pragma unroll
            for (int j = 0; j < 4; ++j) b[j] = (double)Bs[tx * 4 + j][k];
            #pragma unroll
            for (int i = 0; i < 4; ++i)
                #pragma unroll
                for (int j = 0; j < 4; ++j) acc[i][j] += a[i] * b[j];
        }
    }
    #pragma unroll
    for (int i = 0; i < 4; ++i) {
        float4 v = make_float4((float)acc[i][0], (float)acc[i][1],
                               (float)acc[i][2], (float)acc[i][3]);
        *reinterpret_cast<float4*>(&C[(size_t)(m0 + ty * 4 + i) * CIN + n0 + tx * 4]) = v;
    }
}

// ---------------- zi = (z - zq) @ W_in^T via bf16-split MFMA, LDS-staged W ----------------
// Block = 64 tokens (4 waves x 16). W streamed through LDS in 16-neuron tiles,
// single buffer + issue-early/write-late regs (T14), 2 barriers/tile.
__global__ __launch_bounds__(256, 2) void zi_mfma_k(const float* __restrict__ z,
                                                    const float* __restrict__ zq,
                                                    const u16* __restrict__ wh,
                                                    const u16* __restrict__ wl,
                                                    float* __restrict__ zi,
                                                    double* __restrict__ loss_acc,
                                                    int stage0) {
    __shared__ __align__(16) u16 swh[16][520];   // 512 + 8 pad (row 1040B, 16B-aligned)
    __shared__ __align__(16) u16 swl[16][520];
    const int tid = threadIdx.x;
    const int w = tid >> 6;
    const int l = tid & 63;
    const int col = l & 15;
    const int g = l >> 4;
    const int mw = blockIdx.x * 64 + w * 16;
    const int sr = tid >> 4, sq = tid & 15;      // staging row / quarter

    // A fragments: bf16 hi/lo split of residual row (mw+col), k = kc*32 + g*8 + j
    s16x8 ah[16], al[16];
    {
        const float* zr = z  + (size_t)(mw + col) * CIN + g * 8;
        const float* qr = zq + (size_t)(mw + col) * CIN + g * 8;
        #pragma unroll
        for (int kc = 0; kc < 16; ++kc) {
            float4 f0 = *reinterpret_cast<const float4*>(zr + kc * 32);
            float4 f1 = *reinterpret_cast<const float4*>(zr + kc * 32 + 4);
            float f[8] = {f0.x, f0.y, f0.z, f0.w, f1.x, f1.y, f1.z, f1.w};
            if (!stage0) {
                float4 q0 = *reinterpret_cast<const float4*>(qr + kc * 32);
                float4 q1 = *reinterpret_cast<const float4*>(qr + kc * 32 + 4);
                f[0] -= q0.x; f[1] -= q0.y; f[2] -= q0.z; f[3] -= q0.w;
                f[4] -= q1.x; f[5] -= q1.y; f[6] -= q1.z; f[7] -= q1.w;
            }
            #pragma unroll
            for (int j = 0; j < 8; ++j) {
                u16 h = f2bf(f[j]);
                u16 lo = f2bf(f[j] - bf2f(h));
                ah[kc][j] = (short)h; al[kc][j] = (short)lo;
            }
        }
    }

    // staging: thread (sr,sq) covers row sr, 16B chunks {sq, sq+16, sq+32, sq+48} of h and l
    const u16* gh = wh + (size_t)sr * CIN + sq * 8;
    const u16* gl = wl + (size_t)sr * CIN + sq * 8;
    uint4 h0, h1, h2, h3, l0, l1, l2, l3;
    h0 = *(const uint4*)(gh);        h1 = *(const uint4*)(gh + 128);
    h2 = *(const uint4*)(gh + 256);  h3 = *(const uint4*)(gh + 384);
    l0 = *(const uint4*)(gl);        l1 = *(const uint4*)(gl + 128);
    l2 = *(const uint4*)(gl + 256);  l3 = *(const uint4*)(gl + 384);
    *(uint4*)&swh[sr][sq * 8]       = h0;  *(uint4*)&swh[sr][sq * 8 + 128] = h1;
    *(uint4*)&swh[sr][sq * 8 + 256] = h2;  *(uint4*)&swh[sr][sq * 8 + 384] = h3;
    *(uint4*)&swl[sr][sq * 8]       = l0;  *(uint4*)&swl[sr][sq * 8 + 128] = l1;
    *(uint4*)&swl[sr][sq * 8 + 256] = l2;  *(uint4*)&swl[sr][sq * 8 + 384] = l3;

    double zn = 0.0;
    for (int nt = 0; nt < 16; ++nt) {
        __syncthreads();                         // tile nt ready in LDS
        if (nt < 15) {                           // issue next-tile loads early
            const u16* th = gh + (size_t)(nt + 1) * (16 * CIN);
            const u16* tl = gl + (size_t)(nt + 1) * (16 * CIN);
            h0 = *(const uint4*)(th);        h1 = *(const uint4*)(th + 128);
            h2 = *(const uint4*)(th + 256);  h3 = *(const uint4*)(th + 384);
            l0 = *(const uint4*)(tl);        l1 = *(const uint4*)(tl + 128);
            l2 = *(const uint4*)(tl + 256);  l3 = *(const uint4*)(tl + 384);
        }
        f32x4 a0 = {0.f, 0.f, 0.f, 0.f};
        f32x4 a1 = {0.f, 0.f, 0.f, 0.f};
        f32x4 a2 = {0.f, 0.f, 0.f, 0.f};
        #pragma unroll
        for (int kc = 0; kc < 16; ++kc) {
            s16x8 Bh = *(const s16x8*)&swh[col][g * 8 + kc * 32];
            s16x8 Bl = *(const s16x8*)&swl[col][g * 8 + kc * 32];
            a0 = __builtin_amdgcn_mfma_f32_16x16x32_bf16(ah[kc], Bh, a0, 0, 0, 0);
            a1 = __builtin_amdgcn_mfma_f32_16x16x32_bf16(al[kc], Bh, a1, 0, 0, 0);
            a2 = __builtin_amdgcn_mfma_f32_16x16x32_bf16(ah[kc], Bl, a2, 0, 0, 0);
        }
        #pragma unroll
        for (int r = 0; r < 4; ++r) {
            float v = a0[r] + a1[r] + a2[r];
            zi[(size_t)(mw + g * 4 + r) * EMB + nt * 16 + col] = v;
            zn += (double)v * (double)v;
        }
        __syncthreads();                         // all reads of tile nt done
        if (nt < 15) {                           // write tile nt+1
            *(uint4*)&swh[sr][sq * 8]       = h0;  *(uint4*)&swh[sr][sq * 8 + 128] = h1;
            *(uint4*)&swh[sr][sq * 8 + 256] = h2;  *(uint4*)&swh[sr][sq * 8 + 384] = h3;
            *(uint4*)&swl[sr][sq * 8]       = l0;  *(uint4*)&swl[sr][sq * 8 + 128] = l1;
            *(uint4*)&swl[sr][sq * 8 + 256] = l2;  *(uint4*)&swl[sr][sq * 8 + 384] = l3;
        }
    }
    #pragma unroll
    for (int off = 32; off > 0; off >>= 1) zn += __shfl_down(zn, off, 64);
    if (l == 0) atomicAdd(loss_acc, zn);
}

// ---------------- MFMA bf16-split prefilter, LDS-staged codebook ----------------
__global__ __launch_bounds__(256, 2) void pref_k(const float* __restrict__ zi,
                                                 const u16* __restrict__ cbh,
                                                 const u16* __restrict__ cbl,
                                                 const float* __restrict__ vnorm32,
                                                 int* __restrict__ idx,
                                                 int* __restrict__ idx_sum,
                                                 float* __restrict__ mind,
                                                 int* __restrict__ flagged,
                                                 int* __restrict__ cnt,
                                                 double* __restrict__ loss_acc,
                                                 int stage0, int cumprod) {
    __shared__ __align__(16) u16 sbh[16][264];   // 256 + 8 pad (row 528B, 16B-aligned)
    __shared__ __align__(16) u16 sbl[16][264];
    __shared__ double loss_s[16];
    const int tid = threadIdx.x;
    const int w = tid >> 6;
    const int l = tid & 63;
    const int col = l & 15;
    const int g = l >> 4;
    const int mw = blockIdx.x * 64 + w * 16;
    const int sr = tid >> 4, sq = tid & 15;

    s16x8 ah[8], al[8];
    {
        const float* zr = zi + (size_t)(mw + col) * EMB + g * 8;
        #pragma unroll
        for (int kc = 0; kc < 8; ++kc) {
            float4 f0 = *reinterpret_cast<const float4*>(zr + kc * 32);
            float4 f1 = *reinterpret_cast<const float4*>(zr + kc * 32 + 4);
            float f[8] = {f0.x, f0.y, f0.z, f0.w, f1.x, f1.y, f1.z, f1.w};
            #pragma unroll
            for (int j = 0; j < 8; ++j) {
                u16 h = f2bf(f[j]);
                u16 lo = f2bf(f[j] - bf2f(h));
                ah[kc][j] = (short)h;
                al[kc][j] = (short)lo;
            }
        }
    }

    float b1[4] = {1e30f, 1e30f, 1e30f, 1e30f};
    float b2[4] = {1e30f, 1e30f, 1e30f, 1e30f};
    int   i1[4] = {0, 0, 0, 0};

    // staging: thread (sr,sq) covers code-row sr, 16B chunks {sq, sq+16} of h and l
    const u16* gh = cbh + (size_t)sr * EMB + sq * 8;
    const u16* gl = cbl + (size_t)sr * EMB + sq * 8;
    uint4 h0, h1, l0, l1;
    h0 = *(const uint4*)(gh);  h1 = *(const uint4*)(gh + 128);
    l0 = *(const uint4*)(gl);  l1 = *(const uint4*)(gl + 128);
    *(uint4*)&sbh[sr][sq * 8]       = h0;  *(uint4*)&sbh[sr][sq * 8 + 128] = h1;
    *(uint4*)&sbl[sr][sq * 8]       = l0;  *(uint4*)&sbl[sr][sq * 8 + 128] = l1;

    for (int ct = 0; ct < 64; ++ct) {
        __syncthreads();                         // tile ct ready
        if (ct < 63) {
            const u16* th = gh + (size_t)(ct + 1) * (16 * EMB);
            const u16* tl = gl + (size_t)(ct + 1) * (16 * EMB);
            h0 = *(const uint4*)(th);  h1 = *(const uint4*)(th + 128);
            l0 = *(const uint4*)(tl);  l1 = *(const uint4*)(tl + 128);
        }
        const float vn = vnorm32[ct * 16 + col];
        f32x4 a0 = {0.f, 0.f, 0.f, 0.f};
        f32x4 a1 = {0.f, 0.f, 0.f, 0.f};
        f32x4 a2 = {0.f, 0.f, 0.f, 0.f};
        #pragma unroll
        for (int kc = 0; kc < 8; ++kc) {
            s16x8 Bh = *(const s16x8*)&sbh[col][g * 8 + kc * 32];
            s16x8 Bl = *(const s16x8*)&sbl[col][g * 8 + kc * 32];
            a0 = __builtin_amdgcn_mfma_f32_16x16x32_bf16(ah[kc], Bh, a0, 0, 0, 0);
            a1 = __builtin_amdgcn_mfma_f32_16x16x32_bf16(al[kc], Bh, a1, 0, 0, 0);
            a2 = __builtin_amdgcn_mfma_f32_16x16x32_bf16(ah[kc], Bl, a2, 0, 0, 0);
        }
        #pragma unroll
        for (int r = 0; r < 4; ++r) {
            float sc = vn - 2.f * (a0[r] + a1[r] + a2[r]);
            if (sc < b1[r]) { b2[r] = b1[r]; b1[r] = sc; i1[r] = ct * 16 + col; }
            else b2[r] = fminf(b2[r], sc);
        }
        __syncthreads();                         // all reads done
        if (ct < 63) {
            *(uint4*)&sbh[sr][sq * 8]       = h0;  *(uint4*)&sbh[sr][sq * 8 + 128] = h1;
            *(uint4*)&sbl[sr][sq * 8]       = l0;  *(uint4*)&sbl[sr][sq * 8 + 128] = l1;
        }
    }

    #pragma unroll
    for (int off = 1; off < 16; off <<= 1) {
        #pragma unroll
        for (int r = 0; r < 4; ++r) {
            float ob1 = __shfl_xor(b1[r], off, 64);
            int   oi1 = __shfl_xor(i1[r], off, 64);
            float ob2 = __shfl_xor(b2[r], off, 64);
            if (ob1 < b1[r] || (ob1 == b1[r] && oi1 < i1[r])) {
                b2[r] = fminf(b1[r], ob2); b1[r] = ob1; i1[r] = oi1;
            } else {
                b2[r] = fminf(b2[r], ob1);
            }
        }
    }
    if (col == 0) {
        double lsum = 0.0;
        #pragma unroll
        for (int r = 0; r < 4; ++r) {
            int m = mw + g * 4 + r;
            idx[m] = i1[r];
            if (stage0) idx_sum[m] = i1[r];
            else        idx_sum[m] += i1[r] * cumprod;
            mind[m] = b1[r];                 // score-only part
            lsum += (double)b1[r];
            if (b2[r] - b1[r] < DELTA) {
                int slot = atomicAdd(cnt, 1);
                flagged[slot] = m;
            }
        }
        loss_s[w * 4 + g] = lsum;
    }
    __syncthreads();
    if (tid == 0) {
        double s = 0.0;
        #pragma unroll
        for (int q = 0; q < 16; ++q) s += loss_s[q];
        atomicAdd(loss_acc, s);
    }
}

// ---------------- exact fp64 rescan (recomputes zi in fp64) ----------------
__global__ __launch_bounds__(256) void rescan_k(const float* __restrict__ z,
                                                const float* __restrict__ zqv,
                                                const float* __restrict__ Win,
                                                const float* __restrict__ cb,
                                                const double* __restrict__ vnorm64,
                                                const int* __restrict__ flagged,
                                                const int* __restrict__ cnt,
                                                int* __restrict__ idx,
                                                int* __restrict__ idx_sum,
                                                float* __restrict__ mind,
                                                double* __restrict__ loss_acc,
                                                int cumprod, int stage0) {
    __shared__ double r64[CIN];
    __shared__ double zi64[EMB];
    __shared__ double sred[256];
    __shared__ int ired[256];
    int n = *cnt;
    for (int j = blockIdx.x; j < n; j += gridDim.x) {
        int m = flagged[j];
        __syncthreads();
        for (int k = threadIdx.x; k < CIN; k += 256) {
            float rv = z[(size_t)m * CIN + k];
            if (!stage0) rv -= zqv[(size_t)m * CIN + k];   // fp32 subtract (matches ref)
            r64[k] = (double)rv;
        }
        __syncthreads();
        {
            const float* wr = Win + (size_t)threadIdx.x * CIN;
            double s = 0.0;
            for (int k = 0; k < CIN; ++k) s += r64[k] * (double)wr[k];
            zi64[threadIdx.x] = s;
        }
        __syncthreads();
        double best = 1e300; int bi = 0;
        for (int jj = 0; jj < 4; ++jj) {
            int c = threadIdx.x * 4 + jj;   // ascending within thread
            const float* row = cb + (size_t)c * EMB;
            double d = 0.0;
            for (int k = 0; k < EMB; ++k) d += zi64[k] * (double)row[k];
            double sc = vnorm64[c] - 2.0 * d;
            if (sc < best) { best = sc; bi = c; }
        }
        sred[threadIdx.x] = best; ired[threadIdx.x] = bi;
        __syncthreads();
        for (int off = 128; off > 0; off >>= 1) {
            if (threadIdx.x < off) {
                double ob = sred[threadIdx.x + off]; int oi = ired[threadIdx.x + off];
                if (ob < sred[threadIdx.x] ||
                    (ob == sred[threadIdx.x] && oi < ired[threadIdx.x])) {
                    sred[threadIdx.x] = ob; ired[threadIdx.x] = oi;
                }
            }
            __syncthreads();
        }
        if (threadIdx.x == 0) {
            int newI = ired[0], oldI = idx[m];
            if (newI != oldI) { idx[m] = newI; idx_sum[m] += (newI - oldI) * cumprod; }
            atomicAdd(loss_acc, sred[0] - (double)mind[m]);
            mind[m] = (float)sred[0];
        }
        __syncthreads();
    }
}

// ---------------- zq (+)= T[idx]  (row gather); last stage also sums (z - zq)^2 ----------------
__global__ __launch_bounds__(256) void gather_k(const float* __restrict__ T,
                                                const int* __restrict__ idx,
                                                const float* __restrict__ z,
                                                float* __restrict__ zq,
                                                int stage0, int last,
                                                double* __restrict__ loss_acc) {
    __shared__ double red[256];
    int m = blockIdx.x * 16 + (threadIdx.x >> 4);
    int q = threadIdx.x & 15;
    const float* src = T + (size_t)idx[m] * CIN;
    float* dst = zq + (size_t)m * CIN;
    double s = 0.0;
    #pragma unroll
    for (int it = 0; it < 8; ++it) {
        int off = it * 64 + q * 4;
        float4 t = *reinterpret_cast<const float4*>(src + off);
        if (!stage0) {
            float4 o = *reinterpret_cast<const float4*>(dst + off);
            t.x += o.x; t.y += o.y; t.z += o.z; t.w += o.w;
        }
        *reinterpret_cast<float4*>(dst + off) = t;
        if (last) {
            float4 zv = *reinterpret_cast<const float4*>(z + (size_t)m * CIN + off);
            double d0 = (double)zv.x - (double)t.x;
            double d1 = (double)zv.y - (double)t.y;
            double d2 = (double)zv.z - (double)t.z;
            double d3 = (double)zv.w - (double)t.w;
            s += d0 * d0 + d1 * d1 + d2 * d2 + d3 * d3;
        }
    }
    if (last) {
        red[threadIdx.x] = s;
        __syncthreads();
        for (int off = 128; off > 0; off >>= 1) {
            if (threadIdx.x < off) red[threadIdx.x] += red[threadIdx.x + off];
            __syncthreads();
        }
        if (threadIdx.x == 0) atomicAdd(loss_acc + 1, red[0]);
    }
}

// ---------------- finalize ----------------
__global__ void final_k(const int* __restrict__ idx_sum,
                        const double* __restrict__ loss_acc,
                        float* __restrict__ out) {
    int i = blockIdx.x * blockDim.x + threadIdx.x;
    if (i < MTOK) out[MTOK * CIN + i] = (float)idx_sum[i];
    if (i == 0) {
        double loss = 2.0 * loss_acc[0] / (3.0 * (double)MTOK * (double)EMB)
                    + loss_acc[1] / ((double)MTOK * (double)CIN);
        out[MTOK * CIN + MTOK] = (float)loss;
    }
}

extern "C" void kernel_launch(void* const* d_in, const int* in_sizes, int n_in,
                              void* d_out, int out_size, void* d_ws, size_t ws_size,
                              hipStream_t stream) {
    const float* z     = (const float*)d_in[0];
    const float* W_in  = (const float*)d_in[1];
    const float* W_out = (const float*)d_in[2];
    const float* cbs   = (const float*)d_in[3];
    float* out = (float*)d_out;
    char* ws = (char*)d_ws;

    // ws layout (16B-aligned)
    double* vnorm64  = (double*)ws;                               // 24576
    double* loss_acc = (double*)(ws + 24576);                     // 16
    float*  vnorm32  = (float*)(ws + 24592);                      // 12288
    int*    cnt      = (int*)(ws + 36880);                        // 16
    u16*    cbh      = (u16*)(ws + 36896);                        // 1572864
    u16*    cbl      = (u16*)(ws + 1609760);                      // 1572864
    u16*    wh       = (u16*)(ws + 3182624);                      // 786432
    u16*    wl       = (u16*)(ws + 3969056);                      // 786432
    float*  T        = (float*)(ws + 4755488);                    // 6291456
    float*  zi       = (float*)(ws + 11046944);                   // 33554432
    char*   p        = ws + 11046944 + (size_t)MTOK * EMB * 4;
    int*    idx      = (int*)p;                                   // 131072
    int*    idx_sum  = (int*)(p + 131072);                        // 131072
    int*    flagged  = (int*)(p + 262144);                        // 131072
    float*  mind     = (float*)(p + 393216);                      // 131072

    float* zq = out;  // z_q lives in d_out[0 .. MTOK*CIN)

    init_k<<<dim3(1), dim3(1), 0, stream>>>(loss_acc, cnt);
    prep_cb_k<<<dim3(VQ * NCODE), dim3(64), 0, stream>>>(cbs, vnorm64, vnorm32, cbh, cbl);
    prep_w_k<<<dim3(VQ * EMB * CIN / 256), dim3(256), 0, stream>>>(W_in, wh, wl);
    prep_T_k<<<dim3(NCODE / 64, CIN / 64, VQ), dim3(256), 0, stream>>>(cbs, W_out, T);

    const int cumprod[VQ] = {1, 1024, 1024 * 1024};
    for (int i = 0; i < VQ; ++i) {
        const float* cb = cbs + (size_t)i * NCODE * EMB;
        zi_mfma_k<<<dim3(MTOK / 64), dim3(256), 0, stream>>>(
            z, zq, wh + (size_t)i * EMB * CIN, wl + (size_t)i * EMB * CIN,
            zi, loss_acc, i == 0 ? 1 : 0);
        pref_k<<<dim3(MTOK / 64), dim3(256), 0, stream>>>(
            zi, cbh + (size_t)i * NCODE * EMB, cbl + (size_t)i * NCODE * EMB,
            vnorm32 + i * NCODE, idx, idx_sum, mind, flagged, cnt + i, loss_acc,
            i == 0 ? 1 : 0, cumprod[i]);
        rescan_k<<<dim3(512), dim3(256), 0, stream>>>(
            z, zq, W_in + (size_t)i * EMB * CIN, cb, vnorm64 + i * NCODE,
            flagged, cnt + i, idx, idx_sum, mind, loss_acc, cumprod[i],
            i == 0 ? 1 : 0);
        gather_k<<<dim3(MTOK / 16), dim3(256), 0, stream>>>(
            T + (size_t)i * NCODE * CIN, idx, z, zq, i == 0 ? 1 : 0,
            i == VQ - 1 ? 1 : 0, loss_acc);
    }
    final_k<<<dim3(MTOK / 256), dim3(256), 0, stream>>>(idx_sum, loss_acc, out);
}